// Round 1
// baseline (3541.636 us; speedup 1.0000x reference)
//
#include <hip/hip_runtime.h>
#include <math.h>

#define N_NODES 50000
#define N_EDGES 800000

// ---------------------------------------------------------------------------
// Workspace layout (floats):
//   [0]            : int flag (1 if edge_index is int64, 0 if int32)
//   [64]           : deg   [50000]
//   [64+50048]     : dinv  [50000]
//   [64+2*50048]   : h     [50000*128]
//   [.. + 6400000] : agg   [50000*128]
// Total ~51.6 MB.
// ---------------------------------------------------------------------------

// Detect whether edge_index is stored as int64 (values < 50000 -> high words 0).
__global__ void detect_i64_k(const int* ei, int* flag) {
    if (blockIdx.x == 0 && threadIdx.x == 0) {
        int orr = 0;
        for (int i = 0; i < 16; ++i) orr |= ei[2 * i + 1];
        *flag = (orr == 0) ? 1 : 0;
    }
}

__device__ __forceinline__ void load_edge(const void* ei, int is64, int e, int& s, int& d) {
    if (is64) {
        const long long* q = (const long long*)ei;
        s = (int)q[e];
        d = (int)q[N_EDGES + e];
    } else {
        const int* q = (const int*)ei;
        s = q[e];
        d = q[N_EDGES + e];
    }
}

__global__ void deg_init_k(float* deg) {
    int i = blockIdx.x * 256 + threadIdx.x;
    if (i < N_NODES) deg[i] = 1.0f;
}

__global__ void deg_count_k(const void* ei, const int* flag, float* deg) {
    int e = blockIdx.x * 256 + threadIdx.x;
    if (e >= N_EDGES) return;
    int is64 = *flag;
    int s, d;
    load_edge(ei, is64, e, s, d);
    atomicAdd(&deg[d], 1.0f);
}

__global__ void dinv_k(const float* deg, float* dinv) {
    int i = blockIdx.x * 256 + threadIdx.x;
    if (i < N_NODES) dinv[i] = rsqrtf(deg[i]);
}

// C[N x DOUT] = A[N x 128] * W[128 x DOUT], optional relu on A.
// 256 threads; each thread computes 4 rows x 4 cols. W chunk + A^T chunk in LDS.
template <int DOUT, bool RELU>
__global__ __launch_bounds__(256) void matmul_k(const float* __restrict__ A,
                                                const float* __restrict__ W,
                                                float* __restrict__ C) {
    constexpr int CPT = DOUT / 4;     // threads covering the col dimension
    constexpr int GROUPS = 256 / CPT; // row-groups per block
    constexpr int ROWS = GROUPS * 4;  // rows per block
    constexpr int STR = ROWS + 4;     // padded A^T row stride (16B-aligned, bank-spread)
    __shared__ float Ws[64 * DOUT];
    __shared__ float AsT[64 * STR];

    const int tid = threadIdx.x;
    const int g = tid / CPT;
    const int c = (tid % CPT) * 4;
    const int rowBase = blockIdx.x * ROWS;

    float4 acc[4];
#pragma unroll
    for (int r = 0; r < 4; ++r) acc[r] = make_float4(0.f, 0.f, 0.f, 0.f);

    for (int kt = 0; kt < 2; ++kt) {
        __syncthreads();
        // stage W rows [kt*64, kt*64+64) -> Ws
        const float4* Wsrc = (const float4*)(W + kt * 64 * DOUT);
#pragma unroll
        for (int i = tid; i < 16 * DOUT; i += 256) {
            ((float4*)Ws)[i] = Wsrc[i];
        }
        // stage A^T chunk: rows [rowBase, rowBase+ROWS), k in [kt*64, kt*64+64)
#pragma unroll
        for (int i = tid; i < ROWS * 16; i += 256) {
            int r = i >> 4;
            int kk = (i & 15) * 4;
            int grow = rowBase + r;
            float4 v = make_float4(0.f, 0.f, 0.f, 0.f);
            if (grow < N_NODES) v = *(const float4*)(A + (size_t)grow * 128 + kt * 64 + kk);
            if (RELU) {
                v.x = fmaxf(v.x, 0.f); v.y = fmaxf(v.y, 0.f);
                v.z = fmaxf(v.z, 0.f); v.w = fmaxf(v.w, 0.f);
            }
            AsT[(kk + 0) * STR + r] = v.x;
            AsT[(kk + 1) * STR + r] = v.y;
            AsT[(kk + 2) * STR + r] = v.z;
            AsT[(kk + 3) * STR + r] = v.w;
        }
        __syncthreads();
#pragma unroll 8
        for (int k = 0; k < 64; ++k) {
            float4 w4 = *(const float4*)(&Ws[k * DOUT + c]);
            float4 a4 = *(const float4*)(&AsT[k * STR + 4 * g]);
            acc[0].x += a4.x * w4.x; acc[0].y += a4.x * w4.y; acc[0].z += a4.x * w4.z; acc[0].w += a4.x * w4.w;
            acc[1].x += a4.y * w4.x; acc[1].y += a4.y * w4.y; acc[1].z += a4.y * w4.z; acc[1].w += a4.y * w4.w;
            acc[2].x += a4.z * w4.x; acc[2].y += a4.z * w4.y; acc[2].z += a4.z * w4.z; acc[2].w += a4.z * w4.w;
            acc[3].x += a4.w * w4.x; acc[3].y += a4.w * w4.y; acc[3].z += a4.w * w4.z; acc[3].w += a4.w * w4.w;
        }
    }
#pragma unroll
    for (int r = 0; r < 4; ++r) {
        int row = rowBase + g * 4 + r;
        if (row < N_NODES) *(float4*)(C + (size_t)row * DOUT + c) = acc[r];
    }
}

// out[n][:] = h[n][:] * (1/deg[n]) + b[:]   (self-loop contribution + bias)
template <int DOUT>
__global__ __launch_bounds__(256) void node_init_k(const float* __restrict__ h,
                                                   const float* __restrict__ deg,
                                                   const float* __restrict__ b,
                                                   float* __restrict__ out) {
    constexpr int TPN = DOUT / 4;
    int idx = blockIdx.x * 256 + threadIdx.x;
    int n = idx / TPN;
    int p = (idx % TPN) * 4;
    if (n >= N_NODES) return;
    float inv = 1.0f / deg[n];
    float4 hv = *(const float4*)(h + (size_t)n * DOUT + p);
    float4 bv = *(const float4*)(b + p);
    float4 o = make_float4(hv.x * inv + bv.x, hv.y * inv + bv.y,
                           hv.z * inv + bv.z, hv.w * inv + bv.w);
    *(float4*)(out + (size_t)n * DOUT + p) = o;
}

// out[dst][:] += h[src][:] * dinv[src]*dinv[dst]   via atomics
template <int DOUT>
__global__ __launch_bounds__(256) void scatter_k(const float* __restrict__ h,
                                                 const void* ei, const int* flag,
                                                 const float* __restrict__ dinv,
                                                 float* __restrict__ out) {
    constexpr int TPE = DOUT / 4;
    int idx = blockIdx.x * 256 + threadIdx.x;
    int e = idx / TPE;
    int p = (idx % TPE) * 4;
    if (e >= N_EDGES) return;
    int is64 = *flag;
    int s, d;
    load_edge(ei, is64, e, s, d);
    float w = dinv[s] * dinv[d];
    float4 hv = *(const float4*)(h + (size_t)s * DOUT + p);
    float* o = out + (size_t)d * DOUT + p;
    atomicAdd(o + 0, hv.x * w);
    atomicAdd(o + 1, hv.y * w);
    atomicAdd(o + 2, hv.z * w);
    atomicAdd(o + 3, hv.w * w);
}

extern "C" void kernel_launch(void* const* d_in, const int* in_sizes, int n_in,
                              void* d_out, int out_size, void* d_ws, size_t ws_size,
                              hipStream_t stream) {
    const float* x  = (const float*)d_in[0];
    const void*  ei = d_in[1];
    const float* W1 = (const float*)d_in[2];
    const float* b1 = (const float*)d_in[3];
    const float* W2 = (const float*)d_in[4];
    const float* b2 = (const float*)d_in[5];
    const float* W3 = (const float*)d_in[6];
    const float* b3 = (const float*)d_in[7];
    float* out = (float*)d_out;

    float* ws   = (float*)d_ws;
    int*   flag = (int*)d_ws;
    float* deg  = ws + 64;
    float* dinv = deg + 50048;
    float* h    = dinv + 50048;
    float* agg  = h + (size_t)N_NODES * 128;

    const int NB_N  = (N_NODES + 255) / 256;          // 196
    const int NB_E  = (N_EDGES + 255) / 256;          // 3125

    detect_i64_k<<<1, 64, 0, stream>>>((const int*)ei, flag);
    deg_init_k<<<NB_N, 256, 0, stream>>>(deg);
    deg_count_k<<<NB_E, 256, 0, stream>>>(ei, flag, deg);
    dinv_k<<<NB_N, 256, 0, stream>>>(deg, dinv);

    // ---- layer 1: h = x @ W1 ; agg = h/deg + b1 ; agg += scatter(h) ----
    matmul_k<128, false><<<(N_NODES + 31) / 32, 256, 0, stream>>>(x, W1, h);
    node_init_k<128><<<(N_NODES * 32 + 255) / 256, 256, 0, stream>>>(h, deg, b1, agg);
    scatter_k<128><<<(N_EDGES * 32 + 255) / 256, 256, 0, stream>>>(h, ei, flag, dinv, agg);

    // ---- layer 2: h = relu(agg) @ W2 ; agg = h/deg + b2 ; agg += scatter(h) ----
    matmul_k<128, true><<<(N_NODES + 31) / 32, 256, 0, stream>>>(agg, W2, h);
    node_init_k<128><<<(N_NODES * 32 + 255) / 256, 256, 0, stream>>>(h, deg, b2, agg);
    scatter_k<128><<<(N_EDGES * 32 + 255) / 256, 256, 0, stream>>>(h, ei, flag, dinv, agg);

    // ---- layer 3 (to d_out, no relu at end): h3 = relu(agg) @ W3 ----
    matmul_k<64, true><<<(N_NODES + 63) / 64, 256, 0, stream>>>(agg, W3, h);
    node_init_k<64><<<(N_NODES * 16 + 255) / 256, 256, 0, stream>>>(h, deg, b3, out);
    scatter_k<64><<<(N_EDGES * 16 + 255) / 256, 256, 0, stream>>>(h, ei, flag, dinv, out);
}

// Round 3
// 438.921 us; speedup vs baseline: 8.0690x; 8.0690x over previous
//
#include <hip/hip_runtime.h>
#include <math.h>

#define N_NODES 50000
#define N_EDGES 800000

// ---------------------------------------------------------------------------
// Workspace layout:
//   [0]      : int flag (1 if edge_index is int64, 0 if int32)   (64 floats)
//   cnt      : int[50048]    in-degree (no self-loop)
//   dinv     : float[50048]  rsqrt(1+cnt)
//   rowptr   : int[50056]
//   fill     : int[50048]    CSR fill cursors
//   csr_src  : int[800000]
//   csr_w    : float[800000] dinv[src]*dinv[dst]
//   h        : float[50000*128]
//   agg      : float[50000*128]
// Total ~58.6 MB.
// ---------------------------------------------------------------------------

__global__ void detect_i64_k(const int* ei, int* flag) {
    if (blockIdx.x == 0 && threadIdx.x == 0) {
        int orr = 0;
        for (int i = 0; i < 16; ++i) orr |= ei[2 * i + 1];
        *flag = (orr == 0) ? 1 : 0;
    }
}

__device__ __forceinline__ void load_edge(const void* ei, int is64, int e, int& s, int& d) {
    if (is64) {
        const long long* q = (const long long*)ei;
        s = (int)q[e];
        d = (int)q[N_EDGES + e];
    } else {
        const int* q = (const int*)ei;
        s = q[e];
        d = q[N_EDGES + e];
    }
}

__global__ void zero_int_k(int* p, int n) {
    int i = blockIdx.x * 256 + threadIdx.x;
    if (i < n) p[i] = 0;
}

__global__ void deg_count_k(const void* ei, const int* flag, int* cnt) {
    int e = blockIdx.x * 256 + threadIdx.x;
    if (e >= N_EDGES) return;
    int is64 = *flag;
    int s, d;
    load_edge(ei, is64, e, s, d);
    atomicAdd(&cnt[d], 1);
}

__global__ void dinv_k(const int* cnt, float* dinv) {
    int i = blockIdx.x * 256 + threadIdx.x;
    if (i < N_NODES) dinv[i] = rsqrtf(1.0f + (float)cnt[i]);
}

// Single-block exclusive prefix scan over cnt -> rowptr (50001 entries).
__global__ __launch_bounds__(1024) void scan_k(const int* __restrict__ cnt,
                                               int* __restrict__ rowptr) {
    __shared__ int buf[1024];
    __shared__ int carry_s;
    int tid = threadIdx.x;
    if (tid == 0) carry_s = 0;
    __syncthreads();
    for (int base = 0; base < N_NODES; base += 1024) {
        int i = base + tid;
        int v = (i < N_NODES) ? cnt[i] : 0;
        buf[tid] = v;
        __syncthreads();
#pragma unroll
        for (int off = 1; off < 1024; off <<= 1) {
            int t = (tid >= off) ? buf[tid - off] : 0;
            __syncthreads();
            buf[tid] += t;
            __syncthreads();
        }
        int cbase = carry_s;
        int incl = buf[tid];
        if (i < N_NODES) rowptr[i] = cbase + incl - v;
        int total = buf[1023];
        __syncthreads();
        if (tid == 0) carry_s = cbase + total;
        __syncthreads();
    }
    if (tid == 0) rowptr[N_NODES] = carry_s;
}

__global__ void csr_fill_k(const void* ei, const int* flag,
                           const float* __restrict__ dinv,
                           const int* __restrict__ rowptr, int* fill,
                           int* __restrict__ csr_src, float* __restrict__ csr_w) {
    int e = blockIdx.x * 256 + threadIdx.x;
    if (e >= N_EDGES) return;
    int is64 = *flag;
    int s, d;
    load_edge(ei, is64, e, s, d);
    int slot = atomicAdd(&fill[d], 1);
    int pos = rowptr[d] + slot;
    csr_src[pos] = s;
    csr_w[pos] = dinv[s] * dinv[d];
}

// C[N x DOUT] = A[N x 128] * W[128 x DOUT], optional relu on A.
template <int DOUT, bool RELU>
__global__ __launch_bounds__(256) void matmul_k(const float* __restrict__ A,
                                                const float* __restrict__ W,
                                                float* __restrict__ C) {
    constexpr int CPT = DOUT / 4;
    constexpr int GROUPS = 256 / CPT;
    constexpr int ROWS = GROUPS * 4;
    constexpr int STR = ROWS + 4;
    __shared__ float Ws[64 * DOUT];
    __shared__ float AsT[64 * STR];

    const int tid = threadIdx.x;
    const int g = tid / CPT;
    const int c = (tid % CPT) * 4;
    const int rowBase = blockIdx.x * ROWS;

    float4 acc[4];
#pragma unroll
    for (int r = 0; r < 4; ++r) acc[r] = make_float4(0.f, 0.f, 0.f, 0.f);

    for (int kt = 0; kt < 2; ++kt) {
        __syncthreads();
        const float4* Wsrc = (const float4*)(W + kt * 64 * DOUT);
#pragma unroll
        for (int i = tid; i < 16 * DOUT; i += 256) {
            ((float4*)Ws)[i] = Wsrc[i];
        }
#pragma unroll
        for (int i = tid; i < ROWS * 16; i += 256) {
            int r = i >> 4;
            int kk = (i & 15) * 4;
            int grow = rowBase + r;
            float4 v = make_float4(0.f, 0.f, 0.f, 0.f);
            if (grow < N_NODES) v = *(const float4*)(A + (size_t)grow * 128 + kt * 64 + kk);
            if (RELU) {
                v.x = fmaxf(v.x, 0.f); v.y = fmaxf(v.y, 0.f);
                v.z = fmaxf(v.z, 0.f); v.w = fmaxf(v.w, 0.f);
            }
            AsT[(kk + 0) * STR + r] = v.x;
            AsT[(kk + 1) * STR + r] = v.y;
            AsT[(kk + 2) * STR + r] = v.z;
            AsT[(kk + 3) * STR + r] = v.w;
        }
        __syncthreads();
#pragma unroll 8
        for (int k = 0; k < 64; ++k) {
            float4 w4 = *(const float4*)(&Ws[k * DOUT + c]);
            float4 a4 = *(const float4*)(&AsT[k * STR + 4 * g]);
            acc[0].x += a4.x * w4.x; acc[0].y += a4.x * w4.y; acc[0].z += a4.x * w4.z; acc[0].w += a4.x * w4.w;
            acc[1].x += a4.y * w4.x; acc[1].y += a4.y * w4.y; acc[1].z += a4.y * w4.z; acc[1].w += a4.y * w4.w;
            acc[2].x += a4.z * w4.x; acc[2].y += a4.z * w4.y; acc[2].z += a4.z * w4.z; acc[2].w += a4.z * w4.w;
            acc[3].x += a4.w * w4.x; acc[3].y += a4.w * w4.y; acc[3].z += a4.w * w4.z; acc[3].w += a4.w * w4.w;
        }
    }
#pragma unroll
    for (int r = 0; r < 4; ++r) {
        int row = rowBase + g * 4 + r;
        if (row < N_NODES) *(float4*)(C + (size_t)row * DOUT + c) = acc[r];
    }
}

// Pull aggregation: out[n] = sum_{e in CSR[n]} h[src[e]] * w[e]
//                          + h[n]*dinv[n]^2 + b
// TPN lanes per node, float4 per lane (coalesced 4*DOUT-byte row gathers).
template <int DOUT>
__global__ __launch_bounds__(256) void gather_k(const float* __restrict__ h,
                                                const int* __restrict__ rowptr,
                                                const int* __restrict__ csr_src,
                                                const float* __restrict__ csr_w,
                                                const float* __restrict__ dinv,
                                                const float* __restrict__ b,
                                                float* __restrict__ out) {
    constexpr int TPN = DOUT / 4;
    constexpr int NPB = 256 / TPN;
    int n = blockIdx.x * NPB + threadIdx.x / TPN;
    int p = (threadIdx.x % TPN) * 4;
    if (n >= N_NODES) return;
    int beg = rowptr[n];
    int end = rowptr[n + 1];
    float4 acc = make_float4(0.f, 0.f, 0.f, 0.f);
    float4 acc2 = make_float4(0.f, 0.f, 0.f, 0.f);
    int e = beg;
    // 2-way unrolled for MLP (independent gather chains)
    for (; e + 2 <= end; e += 2) {
        int s0 = csr_src[e];
        int s1 = csr_src[e + 1];
        float w0 = csr_w[e];
        float w1 = csr_w[e + 1];
        float4 h0 = *(const float4*)(h + (size_t)s0 * DOUT + p);
        float4 h1 = *(const float4*)(h + (size_t)s1 * DOUT + p);
        acc.x += h0.x * w0; acc.y += h0.y * w0; acc.z += h0.z * w0; acc.w += h0.w * w0;
        acc2.x += h1.x * w1; acc2.y += h1.y * w1; acc2.z += h1.z * w1; acc2.w += h1.w * w1;
    }
    if (e < end) {
        int s0 = csr_src[e];
        float w0 = csr_w[e];
        float4 h0 = *(const float4*)(h + (size_t)s0 * DOUT + p);
        acc.x += h0.x * w0; acc.y += h0.y * w0; acc.z += h0.z * w0; acc.w += h0.w * w0;
    }
    float dn = dinv[n];
    float sw = dn * dn;  // 1/deg
    float4 hv = *(const float4*)(h + (size_t)n * DOUT + p);
    float4 bv = *(const float4*)(b + p);
    float4 o;
    o.x = acc.x + acc2.x + hv.x * sw + bv.x;
    o.y = acc.y + acc2.y + hv.y * sw + bv.y;
    o.z = acc.z + acc2.z + hv.z * sw + bv.z;
    o.w = acc.w + acc2.w + hv.w * sw + bv.w;
    *(float4*)(out + (size_t)n * DOUT + p) = o;
}

extern "C" void kernel_launch(void* const* d_in, const int* in_sizes, int n_in,
                              void* d_out, int out_size, void* d_ws, size_t ws_size,
                              hipStream_t stream) {
    const float* x  = (const float*)d_in[0];
    const void*  ei = d_in[1];
    const float* W1 = (const float*)d_in[2];
    const float* b1 = (const float*)d_in[3];
    const float* W2 = (const float*)d_in[4];
    const float* b2 = (const float*)d_in[5];
    const float* W3 = (const float*)d_in[6];
    const float* b3 = (const float*)d_in[7];
    float* out = (float*)d_out;

    char* wsb = (char*)d_ws;
    int*   flag    = (int*)wsb;                          // 64 floats reserved
    int*   cnt     = (int*)(wsb + 64 * 4);
    float* dinv    = (float*)(wsb + (64 + 50048) * 4);
    int*   rowptr  = (int*)(wsb + (64 + 2 * 50048) * 4);
    int*   fill    = (int*)(wsb + (64 + 2 * 50048 + 50056) * 4);
    int*   csr_src = (int*)(wsb + (64 + 3 * 50048 + 50056) * 4);
    float* csr_w   = (float*)(wsb + (64 + 3 * 50048 + 50056 + 800000) * 4);
    float* h       = (float*)(wsb + (64 + 3 * 50048 + 50056 + 2 * 800000) * 4);
    float* agg     = h + (size_t)N_NODES * 128;

    const int NB_N = (N_NODES + 255) / 256;   // 196
    const int NB_E = (N_EDGES + 255) / 256;   // 3125

    // ---- graph preprocessing (once; reused by all 3 layers) ----
    detect_i64_k<<<1, 64, 0, stream>>>((const int*)ei, flag);
    zero_int_k<<<NB_N, 256, 0, stream>>>(cnt, N_NODES);
    zero_int_k<<<NB_N, 256, 0, stream>>>(fill, N_NODES);
    deg_count_k<<<NB_E, 256, 0, stream>>>(ei, flag, cnt);
    dinv_k<<<NB_N, 256, 0, stream>>>(cnt, dinv);
    scan_k<<<1, 1024, 0, stream>>>(cnt, rowptr);
    csr_fill_k<<<NB_E, 256, 0, stream>>>(ei, flag, dinv, rowptr, fill, csr_src, csr_w);

    // ---- layer 1 ----
    matmul_k<128, false><<<(N_NODES + 31) / 32, 256, 0, stream>>>(x, W1, h);
    gather_k<128><<<(N_NODES + 7) / 8, 256, 0, stream>>>(h, rowptr, csr_src, csr_w, dinv, b1, agg);

    // ---- layer 2 ----
    matmul_k<128, true><<<(N_NODES + 31) / 32, 256, 0, stream>>>(agg, W2, h);
    gather_k<128><<<(N_NODES + 7) / 8, 256, 0, stream>>>(h, rowptr, csr_src, csr_w, dinv, b2, agg);

    // ---- layer 3 (to d_out) ----
    matmul_k<64, true><<<(N_NODES + 63) / 64, 256, 0, stream>>>(agg, W3, h);
    gather_k<64><<<(N_NODES + 15) / 16, 256, 0, stream>>>(h, rowptr, csr_src, csr_w, dinv, b3, out);
}

// Round 4
// 363.600 us; speedup vs baseline: 9.7405x; 1.2072x over previous
//
#include <hip/hip_runtime.h>
#include <math.h>

#define N_NODES 50000
#define N_EDGES 800000
#define SCAN_BLOCKS ((N_NODES + 1023) / 1024)   // 49

// ---------------------------------------------------------------------------
// Workspace layout (ints/floats, 4B each):
//   flag     : int[64]
//   cnt      : int[50048]    in-degree (no self-loop)
//   fill     : int[50048]    CSR fill cursors (adjacent to cnt -> one zero pass)
//   dinv     : float[50048]  rsqrt(1+cnt)
//   rowptr   : int[50056]
//   blocksum : int[64]
//   csr_src  : int[800000]
//   csr_w    : float[800000] dinv[src]*dinv[dst]
//   h        : float[50000*128]
//   agg      : float[50000*128]
// Total ~58.4 MB.
// ---------------------------------------------------------------------------

__global__ void detect_i64_k(const int* ei, int* flag) {
    if (blockIdx.x == 0 && threadIdx.x == 0) {
        int orr = 0;
        for (int i = 0; i < 16; ++i) orr |= ei[2 * i + 1];
        *flag = (orr == 0) ? 1 : 0;
    }
}

__device__ __forceinline__ void load_edge(const void* ei, int is64, int e, int& s, int& d) {
    if (is64) {
        const long long* q = (const long long*)ei;
        s = (int)q[e];
        d = (int)q[N_EDGES + e];
    } else {
        const int* q = (const int*)ei;
        s = q[e];
        d = q[N_EDGES + e];
    }
}

__global__ void zero_int_k(int* p, int n) {
    int i = blockIdx.x * 256 + threadIdx.x;
    if (i < n) p[i] = 0;
}

__global__ void deg_count_k(const void* ei, const int* flag, int* cnt) {
    int e = blockIdx.x * 256 + threadIdx.x;
    if (e >= N_EDGES) return;
    int is64 = *flag;
    int s, d;
    load_edge(ei, is64, e, s, d);
    atomicAdd(&cnt[d], 1);
}

// Phase 1: per-block local exclusive scan of cnt -> rowptr, block sums out.
// Also computes dinv (fused, since cnt is already in registers).
__global__ __launch_bounds__(1024) void scan_pass1_k(const int* __restrict__ cnt,
                                                     int* __restrict__ rowptr,
                                                     int* __restrict__ blocksum,
                                                     float* __restrict__ dinv) {
    __shared__ int buf[1024];
    int tid = threadIdx.x;
    int i = blockIdx.x * 1024 + tid;
    int v = (i < N_NODES) ? cnt[i] : 0;
    if (i < N_NODES) dinv[i] = rsqrtf(1.0f + (float)v);
    buf[tid] = v;
    __syncthreads();
#pragma unroll
    for (int off = 1; off < 1024; off <<= 1) {
        int t = (tid >= off) ? buf[tid - off] : 0;
        __syncthreads();
        buf[tid] += t;
        __syncthreads();
    }
    int incl = buf[tid];
    if (i < N_NODES) rowptr[i] = incl - v;   // local exclusive
    if (tid == 1023) blocksum[blockIdx.x] = incl;
}

// Phase 2: one wave scans the 49 block sums -> exclusive block offsets (in place).
__global__ void scan_pass2_k(int* blocksum, int* rowptr) {
    int tid = threadIdx.x;   // 64 threads
    int v = (tid < SCAN_BLOCKS) ? blocksum[tid] : 0;
    int incl = v;
#pragma unroll
    for (int off = 1; off < 64; off <<= 1) {
        int t = __shfl_up(incl, off);
        if (tid >= off) incl += t;
    }
    if (tid < SCAN_BLOCKS) blocksum[tid] = incl - v;   // exclusive offset
    if (tid == SCAN_BLOCKS - 1) rowptr[N_NODES] = incl;
}

// Phase 3: add block offsets.
__global__ void scan_pass3_k(int* __restrict__ rowptr, const int* __restrict__ blocksum) {
    int i = blockIdx.x * 256 + threadIdx.x;
    if (i < N_NODES) rowptr[i] += blocksum[i >> 10];
}

__global__ void csr_fill_k(const void* ei, const int* flag,
                           const float* __restrict__ dinv,
                           const int* __restrict__ rowptr, int* fill,
                           int* __restrict__ csr_src, float* __restrict__ csr_w) {
    int e = blockIdx.x * 256 + threadIdx.x;
    if (e >= N_EDGES) return;
    int is64 = *flag;
    int s, d;
    load_edge(ei, is64, e, s, d);
    int slot = atomicAdd(&fill[d], 1);
    int pos = rowptr[d] + slot;
    csr_src[pos] = s;
    csr_w[pos] = dinv[s] * dinv[d];
}

// C[N x DOUT] = A[N x 128] * W[128 x DOUT], optional relu on A.
template <int DOUT, bool RELU>
__global__ __launch_bounds__(256) void matmul_k(const float* __restrict__ A,
                                                const float* __restrict__ W,
                                                float* __restrict__ C) {
    constexpr int CPT = DOUT / 4;
    constexpr int GROUPS = 256 / CPT;
    constexpr int ROWS = GROUPS * 4;
    constexpr int STR = ROWS + 4;
    __shared__ float Ws[64 * DOUT];
    __shared__ float AsT[64 * STR];

    const int tid = threadIdx.x;
    const int g = tid / CPT;
    const int c = (tid % CPT) * 4;
    const int rowBase = blockIdx.x * ROWS;

    float4 acc[4];
#pragma unroll
    for (int r = 0; r < 4; ++r) acc[r] = make_float4(0.f, 0.f, 0.f, 0.f);

    for (int kt = 0; kt < 2; ++kt) {
        __syncthreads();
        const float4* Wsrc = (const float4*)(W + kt * 64 * DOUT);
#pragma unroll
        for (int i = tid; i < 16 * DOUT; i += 256) {
            ((float4*)Ws)[i] = Wsrc[i];
        }
#pragma unroll
        for (int i = tid; i < ROWS * 16; i += 256) {
            int r = i >> 4;
            int kk = (i & 15) * 4;
            int grow = rowBase + r;
            float4 v = make_float4(0.f, 0.f, 0.f, 0.f);
            if (grow < N_NODES) v = *(const float4*)(A + (size_t)grow * 128 + kt * 64 + kk);
            if (RELU) {
                v.x = fmaxf(v.x, 0.f); v.y = fmaxf(v.y, 0.f);
                v.z = fmaxf(v.z, 0.f); v.w = fmaxf(v.w, 0.f);
            }
            AsT[(kk + 0) * STR + r] = v.x;
            AsT[(kk + 1) * STR + r] = v.y;
            AsT[(kk + 2) * STR + r] = v.z;
            AsT[(kk + 3) * STR + r] = v.w;
        }
        __syncthreads();
#pragma unroll 8
        for (int k = 0; k < 64; ++k) {
            float4 w4 = *(const float4*)(&Ws[k * DOUT + c]);
            float4 a4 = *(const float4*)(&AsT[k * STR + 4 * g]);
            acc[0].x += a4.x * w4.x; acc[0].y += a4.x * w4.y; acc[0].z += a4.x * w4.z; acc[0].w += a4.x * w4.w;
            acc[1].x += a4.y * w4.x; acc[1].y += a4.y * w4.y; acc[1].z += a4.y * w4.z; acc[1].w += a4.y * w4.w;
            acc[2].x += a4.z * w4.x; acc[2].y += a4.z * w4.y; acc[2].z += a4.z * w4.z; acc[2].w += a4.z * w4.w;
            acc[3].x += a4.w * w4.x; acc[3].y += a4.w * w4.y; acc[3].z += a4.w * w4.z; acc[3].w += a4.w * w4.w;
        }
    }
#pragma unroll
    for (int r = 0; r < 4; ++r) {
        int row = rowBase + g * 4 + r;
        if (row < N_NODES) *(float4*)(C + (size_t)row * DOUT + c) = acc[r];
    }
}

// Pull aggregation: out[n] = sum_{e in CSR[n]} h[src[e]] * w[e] + h[n]*dinv[n]^2 + b
template <int DOUT>
__global__ __launch_bounds__(256) void gather_k(const float* __restrict__ h,
                                                const int* __restrict__ rowptr,
                                                const int* __restrict__ csr_src,
                                                const float* __restrict__ csr_w,
                                                const float* __restrict__ dinv,
                                                const float* __restrict__ b,
                                                float* __restrict__ out) {
    constexpr int TPN = DOUT / 4;
    constexpr int NPB = 256 / TPN;
    int n = blockIdx.x * NPB + threadIdx.x / TPN;
    int p = (threadIdx.x % TPN) * 4;
    if (n >= N_NODES) return;
    int beg = rowptr[n];
    int end = rowptr[n + 1];
    float4 acc = make_float4(0.f, 0.f, 0.f, 0.f);
    float4 acc2 = make_float4(0.f, 0.f, 0.f, 0.f);
    int e = beg;
    for (; e + 2 <= end; e += 2) {
        int s0 = csr_src[e];
        int s1 = csr_src[e + 1];
        float w0 = csr_w[e];
        float w1 = csr_w[e + 1];
        float4 h0 = *(const float4*)(h + (size_t)s0 * DOUT + p);
        float4 h1 = *(const float4*)(h + (size_t)s1 * DOUT + p);
        acc.x += h0.x * w0; acc.y += h0.y * w0; acc.z += h0.z * w0; acc.w += h0.w * w0;
        acc2.x += h1.x * w1; acc2.y += h1.y * w1; acc2.z += h1.z * w1; acc2.w += h1.w * w1;
    }
    if (e < end) {
        int s0 = csr_src[e];
        float w0 = csr_w[e];
        float4 h0 = *(const float4*)(h + (size_t)s0 * DOUT + p);
        acc.x += h0.x * w0; acc.y += h0.y * w0; acc.z += h0.z * w0; acc.w += h0.w * w0;
    }
    float dn = dinv[n];
    float sw = dn * dn;  // 1/deg
    float4 hv = *(const float4*)(h + (size_t)n * DOUT + p);
    float4 bv = *(const float4*)(b + p);
    float4 o;
    o.x = acc.x + acc2.x + hv.x * sw + bv.x;
    o.y = acc.y + acc2.y + hv.y * sw + bv.y;
    o.z = acc.z + acc2.z + hv.z * sw + bv.z;
    o.w = acc.w + acc2.w + hv.w * sw + bv.w;
    *(float4*)(out + (size_t)n * DOUT + p) = o;
}

extern "C" void kernel_launch(void* const* d_in, const int* in_sizes, int n_in,
                              void* d_out, int out_size, void* d_ws, size_t ws_size,
                              hipStream_t stream) {
    const float* x  = (const float*)d_in[0];
    const void*  ei = d_in[1];
    const float* W1 = (const float*)d_in[2];
    const float* b1 = (const float*)d_in[3];
    const float* W2 = (const float*)d_in[4];
    const float* b2 = (const float*)d_in[5];
    const float* W3 = (const float*)d_in[6];
    const float* b3 = (const float*)d_in[7];
    float* out = (float*)d_out;

    char* wsb = (char*)d_ws;
    size_t o = 0;
    int*   flag     = (int*)(wsb + o); o += 64 * 4;
    int*   cnt      = (int*)(wsb + o); o += 50048 * 4;
    int*   fill     = (int*)(wsb + o); o += 50048 * 4;     // adjacent to cnt
    float* dinv     = (float*)(wsb + o); o += 50048 * 4;
    int*   rowptr   = (int*)(wsb + o); o += 50056 * 4;
    int*   blocksum = (int*)(wsb + o); o += 64 * 4;
    int*   csr_src  = (int*)(wsb + o); o += (size_t)N_EDGES * 4;
    float* csr_w    = (float*)(wsb + o); o += (size_t)N_EDGES * 4;
    float* h        = (float*)(wsb + o); o += (size_t)N_NODES * 128 * 4;
    float* agg      = (float*)(wsb + o);

    const int NB_N = (N_NODES + 255) / 256;   // 196
    const int NB_E = (N_EDGES + 255) / 256;   // 3125

    // ---- graph preprocessing (once; reused by all 3 layers) ----
    detect_i64_k<<<1, 64, 0, stream>>>((const int*)ei, flag);
    zero_int_k<<<(2 * 50048 + 255) / 256, 256, 0, stream>>>(cnt, 2 * 50048);  // cnt + fill
    deg_count_k<<<NB_E, 256, 0, stream>>>(ei, flag, cnt);
    scan_pass1_k<<<SCAN_BLOCKS, 1024, 0, stream>>>(cnt, rowptr, blocksum, dinv);
    scan_pass2_k<<<1, 64, 0, stream>>>(blocksum, rowptr);
    scan_pass3_k<<<NB_N, 256, 0, stream>>>(rowptr, blocksum);
    csr_fill_k<<<NB_E, 256, 0, stream>>>(ei, flag, dinv, rowptr, fill, csr_src, csr_w);

    // ---- layer 1 ----
    matmul_k<128, false><<<(N_NODES + 31) / 32, 256, 0, stream>>>(x, W1, h);
    gather_k<128><<<(N_NODES + 7) / 8, 256, 0, stream>>>(h, rowptr, csr_src, csr_w, dinv, b1, agg);

    // ---- layer 2 ----
    matmul_k<128, true><<<(N_NODES + 31) / 32, 256, 0, stream>>>(agg, W2, h);
    gather_k<128><<<(N_NODES + 7) / 8, 256, 0, stream>>>(h, rowptr, csr_src, csr_w, dinv, b2, agg);

    // ---- layer 3 (to d_out) ----
    matmul_k<64, true><<<(N_NODES + 63) / 64, 256, 0, stream>>>(agg, W3, h);
    gather_k<64><<<(N_NODES + 15) / 16, 256, 0, stream>>>(h, rowptr, csr_src, csr_w, dinv, b3, out);
}

// Round 6
// 289.165 us; speedup vs baseline: 12.2478x; 1.2574x over previous
//
#include <hip/hip_runtime.h>
#include <math.h>

#define N_NODES 50000
#define N_EDGES 800000
#define SCAN_BLOCKS ((N_NODES + 1023) / 1024)   // 49

typedef _Float16 half4_t __attribute__((ext_vector_type(4)));
typedef _Float16 half8_t __attribute__((ext_vector_type(8)));

// ---------------------------------------------------------------------------
// Workspace layout:
//   flag     : int[64]
//   cnt      : int[50048]    in-degree (no self-loop)
//   fill     : int[50048]    CSR fill cursors (adjacent to cnt -> one zero pass)
//   dinv     : float[50048]  rsqrt(1+cnt)
//   rowptr   : int[50056]
//   blocksum : int[64]
//   csr_src  : int[800000]
//   csr_w    : float[800000] dinv[src]*dinv[dst]
//   h        : _Float16[50000*128]   (fp16 features for gather)
//   agg      : float[50000*128]
// ---------------------------------------------------------------------------

__global__ void detect_i64_k(const int* ei, int* flag) {
    if (blockIdx.x == 0 && threadIdx.x == 0) {
        int orr = 0;
        for (int i = 0; i < 16; ++i) orr |= ei[2 * i + 1];
        *flag = (orr == 0) ? 1 : 0;
    }
}

__device__ __forceinline__ void load_edge(const void* ei, int is64, int e, int& s, int& d) {
    if (is64) {
        const long long* q = (const long long*)ei;
        s = (int)q[e];
        d = (int)q[N_EDGES + e];
    } else {
        const int* q = (const int*)ei;
        s = q[e];
        d = q[N_EDGES + e];
    }
}

__global__ void zero_int_k(int* p, int n) {
    int i = blockIdx.x * 256 + threadIdx.x;
    if (i < n) p[i] = 0;
}

__global__ void deg_count_k(const void* ei, const int* flag, int* cnt) {
    int e = blockIdx.x * 256 + threadIdx.x;
    if (e >= N_EDGES) return;
    int is64 = *flag;
    int s, d;
    load_edge(ei, is64, e, s, d);
    atomicAdd(&cnt[d], 1);
}

// Phase 1: per-block local exclusive scan of cnt -> rowptr; dinv fused.
__global__ __launch_bounds__(1024) void scan_pass1_k(const int* __restrict__ cnt,
                                                     int* __restrict__ rowptr,
                                                     int* __restrict__ blocksum,
                                                     float* __restrict__ dinv) {
    __shared__ int buf[1024];
    int tid = threadIdx.x;
    int i = blockIdx.x * 1024 + tid;
    int v = (i < N_NODES) ? cnt[i] : 0;
    if (i < N_NODES) dinv[i] = rsqrtf(1.0f + (float)v);
    buf[tid] = v;
    __syncthreads();
#pragma unroll
    for (int off = 1; off < 1024; off <<= 1) {
        int t = (tid >= off) ? buf[tid - off] : 0;
        __syncthreads();
        buf[tid] += t;
        __syncthreads();
    }
    int incl = buf[tid];
    if (i < N_NODES) rowptr[i] = incl - v;   // local exclusive
    if (tid == 1023) blocksum[blockIdx.x] = incl;
}

// Phase 2: one wave scans the 49 block sums -> exclusive block offsets.
__global__ void scan_pass2_k(int* blocksum, int* rowptr) {
    int tid = threadIdx.x;   // 64 threads
    int v = (tid < SCAN_BLOCKS) ? blocksum[tid] : 0;
    int incl = v;
#pragma unroll
    for (int off = 1; off < 64; off <<= 1) {
        int t = __shfl_up(incl, off);
        if (tid >= off) incl += t;
    }
    if (tid < SCAN_BLOCKS) blocksum[tid] = incl - v;
    if (tid == SCAN_BLOCKS - 1) rowptr[N_NODES] = incl;
}

// Phase 3: add block offsets.
__global__ void scan_pass3_k(int* __restrict__ rowptr, const int* __restrict__ blocksum) {
    int i = blockIdx.x * 256 + threadIdx.x;
    if (i < N_NODES) rowptr[i] += blocksum[i >> 10];
}

__global__ void csr_fill_k(const void* ei, const int* flag,
                           const float* __restrict__ dinv,
                           const int* __restrict__ rowptr, int* fill,
                           int* __restrict__ csr_src, float* __restrict__ csr_w) {
    int e = blockIdx.x * 256 + threadIdx.x;
    if (e >= N_EDGES) return;
    int is64 = *flag;
    int s, d;
    load_edge(ei, is64, e, s, d);
    int slot = atomicAdd(&fill[d], 1);
    int pos = rowptr[d] + slot;
    csr_src[pos] = s;
    csr_w[pos] = dinv[s] * dinv[d];
}

// C[N x DOUT] = A[N x 128] * W[128 x DOUT], optional relu on A. f32 compute,
// fp16 output (feeds the gather).
template <int DOUT, bool RELU>
__global__ __launch_bounds__(256) void matmul_k(const float* __restrict__ A,
                                                const float* __restrict__ W,
                                                _Float16* __restrict__ C) {
    constexpr int CPT = DOUT / 4;
    constexpr int GROUPS = 256 / CPT;
    constexpr int ROWS = GROUPS * 4;
    constexpr int STR = ROWS + 4;
    __shared__ float Ws[64 * DOUT];
    __shared__ float AsT[64 * STR];

    const int tid = threadIdx.x;
    const int g = tid / CPT;
    const int c = (tid % CPT) * 4;
    const int rowBase = blockIdx.x * ROWS;

    float4 acc[4];
#pragma unroll
    for (int r = 0; r < 4; ++r) acc[r] = make_float4(0.f, 0.f, 0.f, 0.f);

    for (int kt = 0; kt < 2; ++kt) {
        __syncthreads();
        const float4* Wsrc = (const float4*)(W + kt * 64 * DOUT);
#pragma unroll
        for (int i = tid; i < 16 * DOUT; i += 256) {
            ((float4*)Ws)[i] = Wsrc[i];
        }
#pragma unroll
        for (int i = tid; i < ROWS * 16; i += 256) {
            int r = i >> 4;
            int kk = (i & 15) * 4;
            int grow = rowBase + r;
            float4 v = make_float4(0.f, 0.f, 0.f, 0.f);
            if (grow < N_NODES) v = *(const float4*)(A + (size_t)grow * 128 + kt * 64 + kk);
            if (RELU) {
                v.x = fmaxf(v.x, 0.f); v.y = fmaxf(v.y, 0.f);
                v.z = fmaxf(v.z, 0.f); v.w = fmaxf(v.w, 0.f);
            }
            AsT[(kk + 0) * STR + r] = v.x;
            AsT[(kk + 1) * STR + r] = v.y;
            AsT[(kk + 2) * STR + r] = v.z;
            AsT[(kk + 3) * STR + r] = v.w;
        }
        __syncthreads();
#pragma unroll 8
        for (int k = 0; k < 64; ++k) {
            float4 w4 = *(const float4*)(&Ws[k * DOUT + c]);
            float4 a4 = *(const float4*)(&AsT[k * STR + 4 * g]);
            acc[0].x += a4.x * w4.x; acc[0].y += a4.x * w4.y; acc[0].z += a4.x * w4.z; acc[0].w += a4.x * w4.w;
            acc[1].x += a4.y * w4.x; acc[1].y += a4.y * w4.y; acc[1].z += a4.y * w4.z; acc[1].w += a4.y * w4.w;
            acc[2].x += a4.z * w4.x; acc[2].y += a4.z * w4.y; acc[2].z += a4.z * w4.z; acc[2].w += a4.z * w4.w;
            acc[3].x += a4.w * w4.x; acc[3].y += a4.w * w4.y; acc[3].z += a4.w * w4.z; acc[3].w += a4.w * w4.w;
        }
    }
#pragma unroll
    for (int r = 0; r < 4; ++r) {
        int row = rowBase + g * 4 + r;
        if (row < N_NODES) {
            half4_t hv;
            hv[0] = (_Float16)acc[r].x;
            hv[1] = (_Float16)acc[r].y;
            hv[2] = (_Float16)acc[r].z;
            hv[3] = (_Float16)acc[r].w;
            *(half4_t*)(C + (size_t)row * DOUT + c) = hv;
        }
    }
}

// Pull aggregation: out[n] = sum_{e} h[src[e]]*w[e] + h[n]*dinv[n]^2 + b
// h is fp16; TPN = DOUT/8 lanes per node, each lane loads half8 (16B).
template <int DOUT>
__global__ __launch_bounds__(256) void gather_k(const _Float16* __restrict__ h,
                                                const int* __restrict__ rowptr,
                                                const int* __restrict__ csr_src,
                                                const float* __restrict__ csr_w,
                                                const float* __restrict__ dinv,
                                                const float* __restrict__ b,
                                                float* __restrict__ out) {
    constexpr int TPN = DOUT / 8;
    constexpr int NPB = 256 / TPN;
    int n = blockIdx.x * NPB + threadIdx.x / TPN;
    int li = threadIdx.x % TPN;
    if (n >= N_NODES) return;
    const _Float16* hp = h + li * 8;
    int beg = rowptr[n];
    int end = rowptr[n + 1];
    float acc[8], acc2[8];
#pragma unroll
    for (int j = 0; j < 8; ++j) { acc[j] = 0.f; acc2[j] = 0.f; }
    int e = beg;
    // 4-way unrolled: 4 independent 16B gathers in flight per lane
    for (; e + 4 <= end; e += 4) {
        int s0 = csr_src[e];
        int s1 = csr_src[e + 1];
        int s2 = csr_src[e + 2];
        int s3 = csr_src[e + 3];
        float w0 = csr_w[e];
        float w1 = csr_w[e + 1];
        float w2 = csr_w[e + 2];
        float w3 = csr_w[e + 3];
        half8_t v0 = *(const half8_t*)(hp + (size_t)s0 * DOUT);
        half8_t v1 = *(const half8_t*)(hp + (size_t)s1 * DOUT);
        half8_t v2 = *(const half8_t*)(hp + (size_t)s2 * DOUT);
        half8_t v3 = *(const half8_t*)(hp + (size_t)s3 * DOUT);
#pragma unroll
        for (int j = 0; j < 8; ++j) {
            acc[j] += (float)v0[j] * w0;
            acc2[j] += (float)v1[j] * w1;
            acc[j] += (float)v2[j] * w2;
            acc2[j] += (float)v3[j] * w3;
        }
    }
    for (; e < end; ++e) {
        int s0 = csr_src[e];
        float w0 = csr_w[e];
        half8_t v0 = *(const half8_t*)(hp + (size_t)s0 * DOUT);
#pragma unroll
        for (int j = 0; j < 8; ++j) acc[j] += (float)v0[j] * w0;
    }
    float dn = dinv[n];
    float sw = dn * dn;  // 1/deg
    half8_t hv = *(const half8_t*)(hp + (size_t)n * DOUT);
    float4 bv0 = *(const float4*)(b + li * 8);
    float4 bv1 = *(const float4*)(b + li * 8 + 4);
    float4 o0, o1;
    o0.x = acc[0] + acc2[0] + (float)hv[0] * sw + bv0.x;
    o0.y = acc[1] + acc2[1] + (float)hv[1] * sw + bv0.y;
    o0.z = acc[2] + acc2[2] + (float)hv[2] * sw + bv0.z;
    o0.w = acc[3] + acc2[3] + (float)hv[3] * sw + bv0.w;
    o1.x = acc[4] + acc2[4] + (float)hv[4] * sw + bv1.x;
    o1.y = acc[5] + acc2[5] + (float)hv[5] * sw + bv1.y;
    o1.z = acc[6] + acc2[6] + (float)hv[6] * sw + bv1.z;
    o1.w = acc[7] + acc2[7] + (float)hv[7] * sw + bv1.w;
    float* op = out + (size_t)n * DOUT + li * 8;
    *(float4*)op = o0;
    *(float4*)(op + 4) = o1;
}

extern "C" void kernel_launch(void* const* d_in, const int* in_sizes, int n_in,
                              void* d_out, int out_size, void* d_ws, size_t ws_size,
                              hipStream_t stream) {
    const float* x  = (const float*)d_in[0];
    const void*  ei = d_in[1];
    const float* W1 = (const float*)d_in[2];
    const float* b1 = (const float*)d_in[3];
    const float* W2 = (const float*)d_in[4];
    const float* b2 = (const float*)d_in[5];
    const float* W3 = (const float*)d_in[6];
    const float* b3 = (const float*)d_in[7];
    float* out = (float*)d_out;

    char* wsb = (char*)d_ws;
    size_t o = 0;
    int*   flag     = (int*)(wsb + o); o += 64 * 4;
    int*   cnt      = (int*)(wsb + o); o += 50048 * 4;
    int*   fill     = (int*)(wsb + o); o += 50048 * 4;     // adjacent to cnt
    float* dinv     = (float*)(wsb + o); o += 50048 * 4;
    int*   rowptr   = (int*)(wsb + o); o += 50056 * 4;
    int*   blocksum = (int*)(wsb + o); o += 64 * 4;
    int*   csr_src  = (int*)(wsb + o); o += (size_t)N_EDGES * 4;
    float* csr_w    = (float*)(wsb + o); o += (size_t)N_EDGES * 4;
    _Float16* h     = (_Float16*)(wsb + o); o += (size_t)N_NODES * 128 * 2;
    float* agg      = (float*)(wsb + o);

    const int NB_N = (N_NODES + 255) / 256;   // 196
    const int NB_E = (N_EDGES + 255) / 256;   // 3125

    // ---- graph preprocessing (once; reused by all 3 layers) ----
    detect_i64_k<<<1, 64, 0, stream>>>((const int*)ei, flag);
    zero_int_k<<<(2 * 50048 + 255) / 256, 256, 0, stream>>>(cnt, 2 * 50048);  // cnt + fill
    deg_count_k<<<NB_E, 256, 0, stream>>>(ei, flag, cnt);
    scan_pass1_k<<<SCAN_BLOCKS, 1024, 0, stream>>>(cnt, rowptr, blocksum, dinv);
    scan_pass2_k<<<1, 64, 0, stream>>>(blocksum, rowptr);
    scan_pass3_k<<<NB_N, 256, 0, stream>>>(rowptr, blocksum);
    csr_fill_k<<<NB_E, 256, 0, stream>>>(ei, flag, dinv, rowptr, fill, csr_src, csr_w);

    // ---- layer 1 ----
    matmul_k<128, false><<<(N_NODES + 31) / 32, 256, 0, stream>>>(x, W1, h);
    gather_k<128><<<(N_NODES + 15) / 16, 256, 0, stream>>>(h, rowptr, csr_src, csr_w, dinv, b1, agg);

    // ---- layer 2 ----
    matmul_k<128, true><<<(N_NODES + 31) / 32, 256, 0, stream>>>(agg, W2, h);
    gather_k<128><<<(N_NODES + 15) / 16, 256, 0, stream>>>(h, rowptr, csr_src, csr_w, dinv, b2, agg);

    // ---- layer 3 (to d_out) ----
    matmul_k<64, true><<<(N_NODES + 63) / 64, 256, 0, stream>>>(agg, W3, h);
    gather_k<64><<<(N_NODES + 31) / 32, 256, 0, stream>>>(h, rowptr, csr_src, csr_w, dinv, b3, out);
}

// Round 7
// 242.322 us; speedup vs baseline: 14.6154x; 1.1933x over previous
//
#include <hip/hip_runtime.h>
#include <math.h>

#define N_NODES 50000
#define N_EDGES 800000
#define SCAN_BLOCKS ((N_NODES + 1023) / 1024)   // 49

typedef _Float16 half4_t __attribute__((ext_vector_type(4)));
typedef _Float16 half8_t __attribute__((ext_vector_type(8)));
typedef float floatx4 __attribute__((ext_vector_type(4)));

// ---------------------------------------------------------------------------
// Workspace layout:
//   flag     : int[64]
//   cnt      : int[50048]     in-degree (no self-loop); csr_fill counts it DOWN
//   dinv     : float[50048]   rsqrt(1+deg)
//   rowptr   : int[50056]
//   blocksum : int[64]
//   csr_src  : int[800000]
//   Wt1      : fp16[128*128]  W1^T (cast)
//   Wt2      : fp16[128*128]
//   Wt3      : fp16[64*128]
//   h        : fp16[50000*128]  hs = (A@W)*dinv[row]
//   agg      : fp16[50000*128]  aggregated features (layers 1-2)
// Total ~30 MB.
// ---------------------------------------------------------------------------

__global__ void detect_i64_k(const int* ei, int* flag) {
    if (blockIdx.x == 0 && threadIdx.x == 0) {
        int orr = 0;
        for (int i = 0; i < 16; ++i) orr |= ei[2 * i + 1];
        *flag = (orr == 0) ? 1 : 0;
    }
}

__device__ __forceinline__ void load_edge(const void* ei, int is64, int e, int& s, int& d) {
    if (is64) {
        const long long* q = (const long long*)ei;
        s = (int)q[e];
        d = (int)q[N_EDGES + e];
    } else {
        const int* q = (const int*)ei;
        s = q[e];
        d = q[N_EDGES + e];
    }
}

__global__ void zero_int_k(int* p, int n) {
    int i = blockIdx.x * 256 + threadIdx.x;
    if (i < n) p[i] = 0;
}

__global__ void deg_count_k(const void* ei, const int* flag, int* cnt) {
    int e = blockIdx.x * 256 + threadIdx.x;
    if (e >= N_EDGES) return;
    int is64 = *flag;
    int s, d;
    load_edge(ei, is64, e, s, d);
    atomicAdd(&cnt[d], 1);
}

// Phase 1: per-block local exclusive scan of cnt -> rowptr; dinv fused.
__global__ __launch_bounds__(1024) void scan_pass1_k(const int* __restrict__ cnt,
                                                     int* __restrict__ rowptr,
                                                     int* __restrict__ blocksum,
                                                     float* __restrict__ dinv) {
    __shared__ int buf[1024];
    int tid = threadIdx.x;
    int i = blockIdx.x * 1024 + tid;
    int v = (i < N_NODES) ? cnt[i] : 0;
    if (i < N_NODES) dinv[i] = rsqrtf(1.0f + (float)v);
    buf[tid] = v;
    __syncthreads();
#pragma unroll
    for (int off = 1; off < 1024; off <<= 1) {
        int t = (tid >= off) ? buf[tid - off] : 0;
        __syncthreads();
        buf[tid] += t;
        __syncthreads();
    }
    int incl = buf[tid];
    if (i < N_NODES) rowptr[i] = incl - v;   // local exclusive
    if (tid == 1023) blocksum[blockIdx.x] = incl;
}

// Phase 2: one wave scans the 49 block sums -> exclusive block offsets.
__global__ void scan_pass2_k(int* blocksum, int* rowptr) {
    int tid = threadIdx.x;   // 64 threads
    int v = (tid < SCAN_BLOCKS) ? blocksum[tid] : 0;
    int incl = v;
#pragma unroll
    for (int off = 1; off < 64; off <<= 1) {
        int t = __shfl_up(incl, off);
        if (tid >= off) incl += t;
    }
    if (tid < SCAN_BLOCKS) blocksum[tid] = incl - v;
    if (tid == SCAN_BLOCKS - 1) rowptr[N_NODES] = incl;
}

// Phase 3: add block offsets.
__global__ void scan_pass3_k(int* __restrict__ rowptr, const int* __restrict__ blocksum) {
    int i = blockIdx.x * 256 + threadIdx.x;
    if (i < N_NODES) rowptr[i] += blocksum[i >> 10];
}

// CSR fill: counts cnt DOWN to zero (no separate fill array, no csr_w).
__global__ void csr_fill_k(const void* ei, const int* flag,
                           const int* __restrict__ rowptr, int* cnt,
                           int* __restrict__ csr_src) {
    int e = blockIdx.x * 256 + threadIdx.x;
    if (e >= N_EDGES) return;
    int is64 = *flag;
    int s, d;
    load_edge(ei, is64, e, s, d);
    int slot = atomicSub(&cnt[d], 1) - 1;
    csr_src[rowptr[d] + slot] = s;
}

// Cast + transpose W[128][DOUT] f32 -> Wt[DOUT][128] fp16.
template <int DOUT>
__global__ void wcast_k(const float* __restrict__ W, _Float16* __restrict__ Wt) {
    int i = blockIdx.x * 256 + threadIdx.x;   // over 128*DOUT, exact multiple
    int k = i / DOUT;
    int c = i % DOUT;
    Wt[c * 128 + k] = (_Float16)W[i];
}

// hs[N][DOUT] = (relu(A)[N][128] @ W[128][DOUT]) * dinv[row], fp16 out.
// MFMA 16x16x32 f16, f32 accumulate. 256 thr = 4 waves, 64 rows/block.
template <int DOUT, bool RELU, typename TIN>
__global__ __launch_bounds__(256) void mm_mfma_k(const TIN* __restrict__ A,
                                                 const _Float16* __restrict__ Wt,
                                                 const float* __restrict__ dinv,
                                                 _Float16* __restrict__ C) {
    constexpr int AST = 128 + 8;   // padded fp16 row stride (bank-spread)
    __shared__ _Float16 As[64 * AST];
    __shared__ _Float16 Ws[DOUT * AST];
    const int tid = threadIdx.x;
    const int rowBase = blockIdx.x * 64;

    // ---- stage A (convert to fp16, optional relu) ----
    if constexpr (sizeof(TIN) == 4) {
        for (int i = tid; i < 64 * 32; i += 256) {       // float4 granules
            int r = i >> 5;
            int k4 = (i & 31) * 4;
            int gr = rowBase + r;
            float4 v = make_float4(0.f, 0.f, 0.f, 0.f);
            if (gr < N_NODES) v = *(const float4*)((const float*)A + (size_t)gr * 128 + k4);
            if (RELU) {
                v.x = fmaxf(v.x, 0.f); v.y = fmaxf(v.y, 0.f);
                v.z = fmaxf(v.z, 0.f); v.w = fmaxf(v.w, 0.f);
            }
            half4_t hv;
            hv[0] = (_Float16)v.x; hv[1] = (_Float16)v.y;
            hv[2] = (_Float16)v.z; hv[3] = (_Float16)v.w;
            *(half4_t*)&As[r * AST + k4] = hv;
        }
    } else {
        for (int i = tid; i < 64 * 16; i += 256) {       // half8 granules
            int r = i >> 4;
            int k8 = (i & 15) * 8;
            int gr = rowBase + r;
            half8_t v = {};
            if (gr < N_NODES) v = *(const half8_t*)((const _Float16*)A + (size_t)gr * 128 + k8);
            if (RELU) {
#pragma unroll
                for (int j = 0; j < 8; ++j) v[j] = (v[j] > (_Float16)0) ? v[j] : (_Float16)0;
            }
            *(half8_t*)&As[r * AST + k8] = v;
        }
    }
    // ---- stage Wt ----
    for (int i = tid; i < DOUT * 16; i += 256) {
        int r = i >> 4;
        int k8 = (i & 15) * 8;
        *(half8_t*)&Ws[r * AST + k8] = *(const half8_t*)(Wt + r * 128 + k8);
    }
    __syncthreads();

    const int wid = tid >> 6;
    const int lane = tid & 63;
    const int l15 = lane & 15;
    const int lk = (lane >> 4) * 8;
    const int wrow = wid * 16;

    floatx4 acc[DOUT / 16];
#pragma unroll
    for (int t = 0; t < DOUT / 16; ++t) acc[t] = (floatx4){0.f, 0.f, 0.f, 0.f};

#pragma unroll
    for (int kc = 0; kc < 4; ++kc) {
        half8_t af = *(const half8_t*)&As[(wrow + l15) * AST + kc * 32 + lk];
#pragma unroll
        for (int ct = 0; ct < DOUT / 16; ++ct) {
            half8_t bf = *(const half8_t*)&Ws[(ct * 16 + l15) * AST + kc * 32 + lk];
            acc[ct] = __builtin_amdgcn_mfma_f32_16x16x32_f16(af, bf, acc[ct], 0, 0, 0);
        }
    }

    // D: row = (lane>>4)*4 + q, col = ct*16 + (lane&15)
    int rloc = wrow + (lane >> 4) * 4;
#pragma unroll
    for (int q = 0; q < 4; ++q) {
        int gr = rowBase + rloc + q;
        if (gr < N_NODES) {
            float dn = dinv[gr];
#pragma unroll
            for (int ct = 0; ct < DOUT / 16; ++ct) {
                C[(size_t)gr * DOUT + ct * 16 + l15] = (_Float16)(acc[ct][q] * dn);
            }
        }
    }
}

// Pull aggregation with pre-scaled features:
//   out[n] = dinv[n] * (sum_e hs[src[e]] + hs[n]) + b
template <int DOUT, bool F16OUT>
__global__ __launch_bounds__(256) void gather_k(const _Float16* __restrict__ h,
                                                const int* __restrict__ rowptr,
                                                const int* __restrict__ csr_src,
                                                const float* __restrict__ dinv,
                                                const float* __restrict__ b,
                                                void* __restrict__ out) {
    constexpr int TPN = DOUT / 8;
    constexpr int NPB = 256 / TPN;
    int n = blockIdx.x * NPB + threadIdx.x / TPN;
    int li = threadIdx.x % TPN;
    if (n >= N_NODES) return;
    const _Float16* hp = h + li * 8;
    int beg = rowptr[n];
    int end = rowptr[n + 1];
    float acc[8], acc2[8];
#pragma unroll
    for (int j = 0; j < 8; ++j) { acc[j] = 0.f; acc2[j] = 0.f; }
    int e = beg;
    for (; e + 4 <= end; e += 4) {
        int s0 = csr_src[e];
        int s1 = csr_src[e + 1];
        int s2 = csr_src[e + 2];
        int s3 = csr_src[e + 3];
        half8_t v0 = *(const half8_t*)(hp + (size_t)s0 * DOUT);
        half8_t v1 = *(const half8_t*)(hp + (size_t)s1 * DOUT);
        half8_t v2 = *(const half8_t*)(hp + (size_t)s2 * DOUT);
        half8_t v3 = *(const half8_t*)(hp + (size_t)s3 * DOUT);
#pragma unroll
        for (int j = 0; j < 8; ++j) {
            acc[j] += (float)v0[j];
            acc2[j] += (float)v1[j];
            acc[j] += (float)v2[j];
            acc2[j] += (float)v3[j];
        }
    }
    for (; e < end; ++e) {
        int s0 = csr_src[e];
        half8_t v0 = *(const half8_t*)(hp + (size_t)s0 * DOUT);
#pragma unroll
        for (int j = 0; j < 8; ++j) acc[j] += (float)v0[j];
    }
    float dn = dinv[n];
    half8_t hv = *(const half8_t*)(hp + (size_t)n * DOUT);
    float4 bv0 = *(const float4*)(b + li * 8);
    float4 bv1 = *(const float4*)(b + li * 8 + 4);
    float r[8];
    r[0] = (acc[0] + acc2[0] + (float)hv[0]) * dn + bv0.x;
    r[1] = (acc[1] + acc2[1] + (float)hv[1]) * dn + bv0.y;
    r[2] = (acc[2] + acc2[2] + (float)hv[2]) * dn + bv0.z;
    r[3] = (acc[3] + acc2[3] + (float)hv[3]) * dn + bv0.w;
    r[4] = (acc[4] + acc2[4] + (float)hv[4]) * dn + bv1.x;
    r[5] = (acc[5] + acc2[5] + (float)hv[5]) * dn + bv1.y;
    r[6] = (acc[6] + acc2[6] + (float)hv[6]) * dn + bv1.z;
    r[7] = (acc[7] + acc2[7] + (float)hv[7]) * dn + bv1.w;
    if constexpr (F16OUT) {
        half8_t o;
#pragma unroll
        for (int j = 0; j < 8; ++j) o[j] = (_Float16)r[j];
        *(half8_t*)((_Float16*)out + (size_t)n * DOUT + li * 8) = o;
    } else {
        float* op = (float*)out + (size_t)n * DOUT + li * 8;
        *(float4*)op = make_float4(r[0], r[1], r[2], r[3]);
        *(float4*)(op + 4) = make_float4(r[4], r[5], r[6], r[7]);
    }
}

extern "C" void kernel_launch(void* const* d_in, const int* in_sizes, int n_in,
                              void* d_out, int out_size, void* d_ws, size_t ws_size,
                              hipStream_t stream) {
    const float* x  = (const float*)d_in[0];
    const void*  ei = d_in[1];
    const float* W1 = (const float*)d_in[2];
    const float* b1 = (const float*)d_in[3];
    const float* W2 = (const float*)d_in[4];
    const float* b2 = (const float*)d_in[5];
    const float* W3 = (const float*)d_in[6];
    const float* b3 = (const float*)d_in[7];
    float* out = (float*)d_out;

    char* wsb = (char*)d_ws;
    size_t o = 0;
    int*      flag     = (int*)(wsb + o); o += 64 * 4;
    int*      cnt      = (int*)(wsb + o); o += 50048 * 4;
    float*    dinv     = (float*)(wsb + o); o += 50048 * 4;
    int*      rowptr   = (int*)(wsb + o); o += 50056 * 4;
    int*      blocksum = (int*)(wsb + o); o += 64 * 4;
    int*      csr_src  = (int*)(wsb + o); o += (size_t)N_EDGES * 4;
    _Float16* Wt1      = (_Float16*)(wsb + o); o += 128 * 128 * 2;
    _Float16* Wt2      = (_Float16*)(wsb + o); o += 128 * 128 * 2;
    _Float16* Wt3      = (_Float16*)(wsb + o); o += 64 * 128 * 2;
    _Float16* h        = (_Float16*)(wsb + o); o += (size_t)N_NODES * 128 * 2;
    _Float16* agg      = (_Float16*)(wsb + o);

    const int NB_N = (N_NODES + 255) / 256;   // 196
    const int NB_E = (N_EDGES + 255) / 256;   // 3125
    const int MMB  = (N_NODES + 63) / 64;     // 782

    // ---- graph preprocessing (once; reused by all 3 layers) ----
    detect_i64_k<<<1, 64, 0, stream>>>((const int*)ei, flag);
    zero_int_k<<<NB_N, 256, 0, stream>>>(cnt, 50048);
    deg_count_k<<<NB_E, 256, 0, stream>>>(ei, flag, cnt);
    scan_pass1_k<<<SCAN_BLOCKS, 1024, 0, stream>>>(cnt, rowptr, blocksum, dinv);
    scan_pass2_k<<<1, 64, 0, stream>>>(blocksum, rowptr);
    scan_pass3_k<<<NB_N, 256, 0, stream>>>(rowptr, blocksum);
    csr_fill_k<<<NB_E, 256, 0, stream>>>(ei, flag, rowptr, cnt, csr_src);

    // ---- weight cast/transpose (tiny) ----
    wcast_k<128><<<64, 256, 0, stream>>>(W1, Wt1);
    wcast_k<128><<<64, 256, 0, stream>>>(W2, Wt2);
    wcast_k<64><<<32, 256, 0, stream>>>(W3, Wt3);

    // ---- layer 1 ----
    mm_mfma_k<128, false, float><<<MMB, 256, 0, stream>>>(x, Wt1, dinv, h);
    gather_k<128, true><<<(N_NODES + 15) / 16, 256, 0, stream>>>(h, rowptr, csr_src, dinv, b1, agg);

    // ---- layer 2 ----
    mm_mfma_k<128, true, _Float16><<<MMB, 256, 0, stream>>>(agg, Wt2, dinv, h);
    gather_k<128, true><<<(N_NODES + 15) / 16, 256, 0, stream>>>(h, rowptr, csr_src, dinv, b2, agg);

    // ---- layer 3 (to d_out, f32) ----
    mm_mfma_k<64, true, _Float16><<<MMB, 256, 0, stream>>>(agg, Wt3, dinv, h);
    gather_k<64, false><<<(N_NODES + 31) / 32, 256, 0, stream>>>(h, rowptr, csr_src, dinv, b3, out);
}

// Round 8
// 230.968 us; speedup vs baseline: 15.3339x; 1.0492x over previous
//
#include <hip/hip_runtime.h>
#include <math.h>

#define N_NODES 50000
#define N_EDGES 800000
#define SCAN_BLOCKS ((N_NODES + 1023) / 1024)   // 49

typedef _Float16 half4_t __attribute__((ext_vector_type(4)));
typedef _Float16 half8_t __attribute__((ext_vector_type(8)));
typedef float floatx4 __attribute__((ext_vector_type(4)));

// ---------------------------------------------------------------------------
// Workspace layout:
//   flag     : int[64]
//   cnt      : int[50048]    in-degree (no self-loop)
//   dinv     : float[50048]  rsqrt(1+deg)
//   rowptr   : int[50056]    final global exclusive scan (gather reads this)
//   cursor   : int[50048]    global inclusive scan; csr_fill counts it DOWN
//   blocksum : int[64]
//   ep       : uint[800000]  packed edges (src | dst<<16)
//   csr_src  : ushort[800000]
//   Wt1      : fp16[128*128]  W^T (cast)
//   Wt2      : fp16[128*128]
//   Wt3      : fp16[64*128]
//   h        : fp16[50000*128]  hs = (A@W)*dinv[row]
//   agg      : fp16[50000*128]
// Total ~31.5 MB.
// ---------------------------------------------------------------------------

__device__ __forceinline__ void load_edge(const void* ei, int is64, int e, int& s, int& d) {
    if (is64) {
        const long long* q = (const long long*)ei;
        s = (int)q[e];
        d = (int)q[N_EDGES + e];
    } else {
        const int* q = (const int*)ei;
        s = q[e];
        d = q[N_EDGES + e];
    }
}

// Merged: zero cnt + detect int64-vs-int32 edge layout.
__global__ void init_k(const int* ei, int* flag, int* cnt) {
    int i = blockIdx.x * 256 + threadIdx.x;
    if (i < 50048) cnt[i] = 0;
    if (i == 0) {
        int orr = 0;
        for (int j = 0; j < 16; ++j) orr |= ei[2 * j + 1];
        *flag = (orr == 0) ? 1 : 0;
    }
}

// Histogram + compact the edge list into 4B packed form (node ids < 2^16).
__global__ void deg_compact_k(const void* ei, const int* flag, int* cnt,
                              unsigned int* __restrict__ ep) {
    int e = blockIdx.x * 256 + threadIdx.x;
    if (e >= N_EDGES) return;
    int is64 = *flag;
    int s, d;
    load_edge(ei, is64, e, s, d);
    ep[e] = (unsigned int)s | ((unsigned int)d << 16);
    atomicAdd(&cnt[d], 1);
}

// Phase 1: per-block local scans of cnt; dinv fused.
// rowptr[i] = local exclusive, cursor[i] = local inclusive.
__global__ __launch_bounds__(1024) void scan_pass1_k(const int* __restrict__ cnt,
                                                     int* __restrict__ rowptr,
                                                     int* __restrict__ cursor,
                                                     int* __restrict__ blocksum,
                                                     float* __restrict__ dinv) {
    __shared__ int buf[1024];
    int tid = threadIdx.x;
    int i = blockIdx.x * 1024 + tid;
    int v = (i < N_NODES) ? cnt[i] : 0;
    if (i < N_NODES) dinv[i] = rsqrtf(1.0f + (float)v);
    buf[tid] = v;
    __syncthreads();
#pragma unroll
    for (int off = 1; off < 1024; off <<= 1) {
        int t = (tid >= off) ? buf[tid - off] : 0;
        __syncthreads();
        buf[tid] += t;
        __syncthreads();
    }
    int incl = buf[tid];
    if (i < N_NODES) {
        rowptr[i] = incl - v;
        cursor[i] = incl;
    }
    if (tid == 1023) blocksum[blockIdx.x] = incl;
}

// Phase 2: one wave scans the 49 block sums -> exclusive block offsets.
__global__ void scan_pass2_k(int* blocksum, int* rowptr) {
    int tid = threadIdx.x;   // 64 threads
    int v = (tid < SCAN_BLOCKS) ? blocksum[tid] : 0;
    int incl = v;
#pragma unroll
    for (int off = 1; off < 64; off <<= 1) {
        int t = __shfl_up(incl, off);
        if (tid >= off) incl += t;
    }
    if (tid < SCAN_BLOCKS) blocksum[tid] = incl - v;
    if (tid == SCAN_BLOCKS - 1) rowptr[N_NODES] = incl;
}

// Phase 3: add block offsets to both rowptr and cursor.
__global__ void scan_pass3_k(int* __restrict__ rowptr, int* __restrict__ cursor,
                             const int* __restrict__ blocksum) {
    int i = blockIdx.x * 256 + threadIdx.x;
    if (i < N_NODES) {
        int bs = blocksum[i >> 10];
        rowptr[i] += bs;
        cursor[i] += bs;
    }
}

// CSR fill: read packed edge (4B), count cursor down, 2B store.
__global__ void csr_fill_k(const unsigned int* __restrict__ ep, int* cursor,
                           unsigned short* __restrict__ csr_src) {
    int e = blockIdx.x * 256 + threadIdx.x;
    if (e >= N_EDGES) return;
    unsigned int p = ep[e];
    int s = (int)(p & 0xFFFFu);
    int d = (int)(p >> 16);
    int slot = atomicSub(&cursor[d], 1) - 1;
    csr_src[slot] = (unsigned short)s;
}

// Cast + transpose all three weight matrices in one launch.
__global__ void wcast_all_k(const float* __restrict__ W1, const float* __restrict__ W2,
                            const float* __restrict__ W3,
                            _Float16* __restrict__ Wt1, _Float16* __restrict__ Wt2,
                            _Float16* __restrict__ Wt3) {
    int i = blockIdx.x * 256 + threadIdx.x;   // 0..40959
    if (i < 16384) {
        int k = i >> 7, c = i & 127;           // W1[128][128]
        Wt1[c * 128 + k] = (_Float16)W1[i];
    } else if (i < 32768) {
        int j = i - 16384;
        int k = j >> 7, c = j & 127;           // W2[128][128]
        Wt2[c * 128 + k] = (_Float16)W2[j];
    } else if (i < 40960) {
        int j = i - 32768;
        int k = j >> 6, c = j & 63;            // W3[128][64]
        Wt3[c * 128 + k] = (_Float16)W3[j];
    }
}

// hs[N][DOUT] = (relu(A)[N][128] @ W[128][DOUT]) * dinv[row], fp16 out.
// MFMA 16x16x32 f16, f32 accumulate. 256 thr = 4 waves, 64 rows/block.
template <int DOUT, bool RELU, typename TIN>
__global__ __launch_bounds__(256) void mm_mfma_k(const TIN* __restrict__ A,
                                                 const _Float16* __restrict__ Wt,
                                                 const float* __restrict__ dinv,
                                                 _Float16* __restrict__ C) {
    constexpr int AST = 128 + 8;   // padded fp16 row stride (bank-spread)
    __shared__ _Float16 As[64 * AST];
    __shared__ _Float16 Ws[DOUT * AST];
    const int tid = threadIdx.x;
    const int rowBase = blockIdx.x * 64;

    // ---- stage A (convert to fp16, optional relu) ----
    if constexpr (sizeof(TIN) == 4) {
        for (int i = tid; i < 64 * 32; i += 256) {       // float4 granules
            int r = i >> 5;
            int k4 = (i & 31) * 4;
            int gr = rowBase + r;
            float4 v = make_float4(0.f, 0.f, 0.f, 0.f);
            if (gr < N_NODES) v = *(const float4*)((const float*)A + (size_t)gr * 128 + k4);
            if (RELU) {
                v.x = fmaxf(v.x, 0.f); v.y = fmaxf(v.y, 0.f);
                v.z = fmaxf(v.z, 0.f); v.w = fmaxf(v.w, 0.f);
            }
            half4_t hv;
            hv[0] = (_Float16)v.x; hv[1] = (_Float16)v.y;
            hv[2] = (_Float16)v.z; hv[3] = (_Float16)v.w;
            *(half4_t*)&As[r * AST + k4] = hv;
        }
    } else {
        for (int i = tid; i < 64 * 16; i += 256) {       // half8 granules
            int r = i >> 4;
            int k8 = (i & 15) * 8;
            int gr = rowBase + r;
            half8_t v = {};
            if (gr < N_NODES) v = *(const half8_t*)((const _Float16*)A + (size_t)gr * 128 + k8);
            if (RELU) {
#pragma unroll
                for (int j = 0; j < 8; ++j) v[j] = (v[j] > (_Float16)0) ? v[j] : (_Float16)0;
            }
            *(half8_t*)&As[r * AST + k8] = v;
        }
    }
    // ---- stage Wt ----
    for (int i = tid; i < DOUT * 16; i += 256) {
        int r = i >> 4;
        int k8 = (i & 15) * 8;
        *(half8_t*)&Ws[r * AST + k8] = *(const half8_t*)(Wt + r * 128 + k8);
    }
    __syncthreads();

    const int wid = tid >> 6;
    const int lane = tid & 63;
    const int l15 = lane & 15;
    const int lk = (lane >> 4) * 8;
    const int wrow = wid * 16;

    floatx4 acc[DOUT / 16];
#pragma unroll
    for (int t = 0; t < DOUT / 16; ++t) acc[t] = (floatx4){0.f, 0.f, 0.f, 0.f};

#pragma unroll
    for (int kc = 0; kc < 4; ++kc) {
        half8_t af = *(const half8_t*)&As[(wrow + l15) * AST + kc * 32 + lk];
#pragma unroll
        for (int ct = 0; ct < DOUT / 16; ++ct) {
            half8_t bf = *(const half8_t*)&Ws[(ct * 16 + l15) * AST + kc * 32 + lk];
            acc[ct] = __builtin_amdgcn_mfma_f32_16x16x32_f16(af, bf, acc[ct], 0, 0, 0);
        }
    }

    // D: row = (lane>>4)*4 + q, col = ct*16 + (lane&15)
    int rloc = wrow + (lane >> 4) * 4;
#pragma unroll
    for (int q = 0; q < 4; ++q) {
        int gr = rowBase + rloc + q;
        if (gr < N_NODES) {
            float dn = dinv[gr];
#pragma unroll
            for (int ct = 0; ct < DOUT / 16; ++ct) {
                C[(size_t)gr * DOUT + ct * 16 + l15] = (_Float16)(acc[ct][q] * dn);
            }
        }
    }
}

// Pull aggregation with pre-scaled features:
//   out[n] = dinv[n] * (sum_e hs[src[e]] + hs[n]) + b
template <int DOUT, bool F16OUT>
__global__ __launch_bounds__(256) void gather_k(const _Float16* __restrict__ h,
                                                const int* __restrict__ rowptr,
                                                const unsigned short* __restrict__ csr_src,
                                                const float* __restrict__ dinv,
                                                const float* __restrict__ b,
                                                void* __restrict__ out) {
    constexpr int TPN = DOUT / 8;
    constexpr int NPB = 256 / TPN;
    int n = blockIdx.x * NPB + threadIdx.x / TPN;
    int li = threadIdx.x % TPN;
    if (n >= N_NODES) return;
    const _Float16* hp = h + li * 8;
    int beg = rowptr[n];
    int end = rowptr[n + 1];
    float acc[8], acc2[8];
#pragma unroll
    for (int j = 0; j < 8; ++j) { acc[j] = 0.f; acc2[j] = 0.f; }
    int e = beg;
    for (; e + 4 <= end; e += 4) {
        int s0 = csr_src[e];
        int s1 = csr_src[e + 1];
        int s2 = csr_src[e + 2];
        int s3 = csr_src[e + 3];
        half8_t v0 = *(const half8_t*)(hp + (size_t)s0 * DOUT);
        half8_t v1 = *(const half8_t*)(hp + (size_t)s1 * DOUT);
        half8_t v2 = *(const half8_t*)(hp + (size_t)s2 * DOUT);
        half8_t v3 = *(const half8_t*)(hp + (size_t)s3 * DOUT);
#pragma unroll
        for (int j = 0; j < 8; ++j) {
            acc[j] += (float)v0[j];
            acc2[j] += (float)v1[j];
            acc[j] += (float)v2[j];
            acc2[j] += (float)v3[j];
        }
    }
    for (; e < end; ++e) {
        int s0 = csr_src[e];
        half8_t v0 = *(const half8_t*)(hp + (size_t)s0 * DOUT);
#pragma unroll
        for (int j = 0; j < 8; ++j) acc[j] += (float)v0[j];
    }
    float dn = dinv[n];
    half8_t hv = *(const half8_t*)(hp + (size_t)n * DOUT);
    float4 bv0 = *(const float4*)(b + li * 8);
    float4 bv1 = *(const float4*)(b + li * 8 + 4);
    float r[8];
    r[0] = (acc[0] + acc2[0] + (float)hv[0]) * dn + bv0.x;
    r[1] = (acc[1] + acc2[1] + (float)hv[1]) * dn + bv0.y;
    r[2] = (acc[2] + acc2[2] + (float)hv[2]) * dn + bv0.z;
    r[3] = (acc[3] + acc2[3] + (float)hv[3]) * dn + bv0.w;
    r[4] = (acc[4] + acc2[4] + (float)hv[4]) * dn + bv1.x;
    r[5] = (acc[5] + acc2[5] + (float)hv[5]) * dn + bv1.y;
    r[6] = (acc[6] + acc2[6] + (float)hv[6]) * dn + bv1.z;
    r[7] = (acc[7] + acc2[7] + (float)hv[7]) * dn + bv1.w;
    if constexpr (F16OUT) {
        half8_t o;
#pragma unroll
        for (int j = 0; j < 8; ++j) o[j] = (_Float16)r[j];
        *(half8_t*)((_Float16*)out + (size_t)n * DOUT + li * 8) = o;
    } else {
        float* op = (float*)out + (size_t)n * DOUT + li * 8;
        *(float4*)op = make_float4(r[0], r[1], r[2], r[3]);
        *(float4*)(op + 4) = make_float4(r[4], r[5], r[6], r[7]);
    }
}

extern "C" void kernel_launch(void* const* d_in, const int* in_sizes, int n_in,
                              void* d_out, int out_size, void* d_ws, size_t ws_size,
                              hipStream_t stream) {
    const float* x  = (const float*)d_in[0];
    const void*  ei = d_in[1];
    const float* W1 = (const float*)d_in[2];
    const float* b1 = (const float*)d_in[3];
    const float* W2 = (const float*)d_in[4];
    const float* b2 = (const float*)d_in[5];
    const float* W3 = (const float*)d_in[6];
    const float* b3 = (const float*)d_in[7];
    float* out = (float*)d_out;

    char* wsb = (char*)d_ws;
    size_t o = 0;
    int*            flag     = (int*)(wsb + o); o += 64 * 4;
    int*            cnt      = (int*)(wsb + o); o += 50048 * 4;
    float*          dinv     = (float*)(wsb + o); o += 50048 * 4;
    int*            rowptr   = (int*)(wsb + o); o += 50056 * 4;
    int*            cursor   = (int*)(wsb + o); o += 50048 * 4;
    int*            blocksum = (int*)(wsb + o); o += 64 * 4;
    unsigned int*   ep       = (unsigned int*)(wsb + o); o += (size_t)N_EDGES * 4;
    unsigned short* csr_src  = (unsigned short*)(wsb + o); o += (size_t)N_EDGES * 2;
    _Float16*       Wt1      = (_Float16*)(wsb + o); o += 128 * 128 * 2;
    _Float16*       Wt2      = (_Float16*)(wsb + o); o += 128 * 128 * 2;
    _Float16*       Wt3      = (_Float16*)(wsb + o); o += 64 * 128 * 2;
    _Float16*       h        = (_Float16*)(wsb + o); o += (size_t)N_NODES * 128 * 2;
    _Float16*       agg      = (_Float16*)(wsb + o);

    const int NB_N = (N_NODES + 255) / 256;   // 196
    const int NB_E = (N_EDGES + 255) / 256;   // 3125
    const int MMB  = (N_NODES + 63) / 64;     // 782

    // ---- graph preprocessing (once; reused by all 3 layers) ----
    init_k<<<NB_N, 256, 0, stream>>>((const int*)ei, flag, cnt);
    deg_compact_k<<<NB_E, 256, 0, stream>>>(ei, flag, cnt, ep);
    scan_pass1_k<<<SCAN_BLOCKS, 1024, 0, stream>>>(cnt, rowptr, cursor, blocksum, dinv);
    scan_pass2_k<<<1, 64, 0, stream>>>(blocksum, rowptr);
    scan_pass3_k<<<NB_N, 256, 0, stream>>>(rowptr, cursor, blocksum);
    csr_fill_k<<<NB_E, 256, 0, stream>>>(ep, cursor, csr_src);
    wcast_all_k<<<160, 256, 0, stream>>>(W1, W2, W3, Wt1, Wt2, Wt3);

    // ---- layer 1 ----
    mm_mfma_k<128, false, float><<<MMB, 256, 0, stream>>>(x, Wt1, dinv, h);
    gather_k<128, true><<<(N_NODES + 15) / 16, 256, 0, stream>>>(h, rowptr, csr_src, dinv, b1, agg);

    // ---- layer 2 ----
    mm_mfma_k<128, true, _Float16><<<MMB, 256, 0, stream>>>(agg, Wt2, dinv, h);
    gather_k<128, true><<<(N_NODES + 15) / 16, 256, 0, stream>>>(h, rowptr, csr_src, dinv, b2, agg);

    // ---- layer 3 (to d_out, f32) ----
    mm_mfma_k<64, true, _Float16><<<MMB, 256, 0, stream>>>(agg, Wt3, dinv, h);
    gather_k<64, false><<<(N_NODES + 31) / 32, 256, 0, stream>>>(h, rowptr, csr_src, dinv, b3, out);
}

// Round 9
// 207.860 us; speedup vs baseline: 17.0386x; 1.1112x over previous
//
#include <hip/hip_runtime.h>
#include <math.h>

#define N_NODES 50000
#define N_EDGES 800000
#define SCAN_BLOCKS ((N_NODES + 1023) / 1024)   // 49
#define BSH 7                                    // 128 nodes per bucket
#define BNODES 128
#define NBKT ((N_NODES + BNODES - 1) / BNODES)   // 391
#define EPW 4096                                 // edges per workgroup in bucketA
#define NWG_A ((N_EDGES + EPW - 1) / EPW)        // 196

typedef _Float16 half4_t __attribute__((ext_vector_type(4)));
typedef _Float16 half8_t __attribute__((ext_vector_type(8)));
typedef float floatx4 __attribute__((ext_vector_type(4)));

// ---------------------------------------------------------------------------
// Workspace layout:
//   flag     : int[64]
//   cnt      : int[50048]    in-degree (no self-loop)
//   dinv     : float[50048]  rsqrt(1+deg)
//   rowptr   : int[50056]    global exclusive scan (gather + buckets read this)
//   blocksum : int[64]
//   bcur     : int[448]      per-bucket reservation cursors (init = rowptr[b*128])
//   ep       : uint[800000]  packed edges (src | dst<<16)
//   ep2      : uint[800000]  bucket-grouped packed edges
//   csr_src  : ushort[800000]
//   Wt1/2/3  : fp16 W^T
//   h        : fp16[50000*128]
//   agg      : fp16[50000*128]
// ---------------------------------------------------------------------------

__device__ __forceinline__ void load_edge(const void* ei, int is64, int e, int& s, int& d) {
    if (is64) {
        const long long* q = (const long long*)ei;
        s = (int)q[e];
        d = (int)q[N_EDGES + e];
    } else {
        const int* q = (const int*)ei;
        s = q[e];
        d = q[N_EDGES + e];
    }
}

// Merged: zero cnt + detect i64 + weight cast/transpose (independent preprocessing).
__global__ void init_k(const int* ei, int* flag, int* cnt,
                       const float* __restrict__ W1, const float* __restrict__ W2,
                       const float* __restrict__ W3,
                       _Float16* __restrict__ Wt1, _Float16* __restrict__ Wt2,
                       _Float16* __restrict__ Wt3) {
    int i = blockIdx.x * 256 + threadIdx.x;
    if (i < 50048) cnt[i] = 0;
    if (i == 0) {
        int orr = 0;
        for (int j = 0; j < 16; ++j) orr |= ei[2 * j + 1];
        *flag = (orr == 0) ? 1 : 0;
    }
    if (i < 16384) {
        int k = i >> 7, c = i & 127;           // W1[128][128]
        Wt1[c * 128 + k] = (_Float16)W1[i];
    } else if (i < 32768) {
        int j = i - 16384;
        int k = j >> 7, c = j & 127;           // W2[128][128]
        Wt2[c * 128 + k] = (_Float16)W2[j];
    } else if (i < 40960) {
        int j = i - 32768;
        int k = j >> 6, c = j & 63;            // W3[128][64]
        Wt3[c * 128 + k] = (_Float16)W3[j];
    }
}

// Histogram + compact the edge list into 4B packed form (node ids < 2^16).
__global__ void deg_compact_k(const void* ei, const int* flag, int* cnt,
                              unsigned int* __restrict__ ep) {
    int e = blockIdx.x * 256 + threadIdx.x;
    if (e >= N_EDGES) return;
    int is64 = *flag;
    int s, d;
    load_edge(ei, is64, e, s, d);
    ep[e] = (unsigned int)s | ((unsigned int)d << 16);
    atomicAdd(&cnt[d], 1);
}

// Phase 1: per-block local exclusive scan of cnt -> rowptr; dinv fused.
__global__ __launch_bounds__(1024) void scan_pass1_k(const int* __restrict__ cnt,
                                                     int* __restrict__ rowptr,
                                                     int* __restrict__ blocksum,
                                                     float* __restrict__ dinv) {
    __shared__ int buf[1024];
    int tid = threadIdx.x;
    int i = blockIdx.x * 1024 + tid;
    int v = (i < N_NODES) ? cnt[i] : 0;
    if (i < N_NODES) dinv[i] = rsqrtf(1.0f + (float)v);
    buf[tid] = v;
    __syncthreads();
#pragma unroll
    for (int off = 1; off < 1024; off <<= 1) {
        int t = (tid >= off) ? buf[tid - off] : 0;
        __syncthreads();
        buf[tid] += t;
        __syncthreads();
    }
    int incl = buf[tid];
    if (i < N_NODES) rowptr[i] = incl - v;   // local exclusive
    if (tid == 1023) blocksum[blockIdx.x] = incl;
}

// Phase 2: one wave scans the 49 block sums -> exclusive block offsets.
__global__ void scan_pass2_k(int* blocksum, int* rowptr) {
    int tid = threadIdx.x;   // 64 threads
    int v = (tid < SCAN_BLOCKS) ? blocksum[tid] : 0;
    int incl = v;
#pragma unroll
    for (int off = 1; off < 64; off <<= 1) {
        int t = __shfl_up(incl, off);
        if (tid >= off) incl += t;
    }
    if (tid < SCAN_BLOCKS) blocksum[tid] = incl - v;
    if (tid == SCAN_BLOCKS - 1) rowptr[N_NODES] = incl;
}

// Phase 3: add block offsets; emit per-bucket reservation cursors.
__global__ void scan_pass3_k(int* __restrict__ rowptr, const int* __restrict__ blocksum,
                             int* __restrict__ bcur) {
    int i = blockIdx.x * 256 + threadIdx.x;
    if (i < N_NODES) {
        int v = rowptr[i] + blocksum[i >> 10];
        rowptr[i] = v;
        if ((i & (BNODES - 1)) == 0) bcur[i >> BSH] = v;
    }
}

// Bucket pass A: group edges by dst-bucket (128 nodes / bucket).
// Per-wg LDS histogram -> one global reservation per (wg,bucket) -> scatter.
__global__ __launch_bounds__(256) void bucketA_k(const unsigned int* __restrict__ ep,
                                                 int* bcur,
                                                 unsigned int* __restrict__ ep2) {
    __shared__ int hist[NBKT];
    __shared__ int gofs[NBKT];
    __shared__ int lcur[NBKT];
    int tid = threadIdx.x;
    for (int i = tid; i < NBKT; i += 256) { hist[i] = 0; lcur[i] = 0; }
    __syncthreads();
    int base = blockIdx.x * EPW;
    unsigned int pv[EPW / 256];
#pragma unroll
    for (int j = 0; j < EPW / 256; ++j) {
        int e = base + j * 256 + tid;
        unsigned int p = (e < N_EDGES) ? ep[e] : 0xFFFFFFFFu;
        pv[j] = p;
        if (p != 0xFFFFFFFFu) atomicAdd(&hist[(p >> 16) >> BSH], 1);
    }
    __syncthreads();
    for (int i = tid; i < NBKT; i += 256)
        gofs[i] = hist[i] ? atomicAdd(&bcur[i], hist[i]) : 0;
    __syncthreads();
#pragma unroll
    for (int j = 0; j < EPW / 256; ++j) {
        unsigned int p = pv[j];
        if (p == 0xFFFFFFFFu) continue;
        int b = (int)((p >> 16) >> BSH);
        int pos = gofs[b] + atomicAdd(&lcur[b], 1);
        ep2[pos] = p;
    }
}

// Bucket pass B: one wg per bucket; node cursors in LDS; private 4KB store region.
__global__ __launch_bounds__(256) void bucketB_k(const unsigned int* __restrict__ ep2,
                                                 const int* __restrict__ rowptr,
                                                 unsigned short* __restrict__ csr_src) {
    __shared__ int lcur[BNODES];
    int b = blockIdx.x;
    int lo = b << BSH;
    int hi = min(lo + BNODES, N_NODES);
    int tid = threadIdx.x;
    if (tid < hi - lo) lcur[tid] = rowptr[lo + tid];
    __syncthreads();
    int beg = rowptr[lo];
    int end = rowptr[hi];
    for (int j = beg + tid; j < end; j += 256) {
        unsigned int p = ep2[j];
        int s = (int)(p & 0xFFFFu);
        int d = (int)(p >> 16);
        int slot = atomicAdd(&lcur[d - lo], 1);
        csr_src[slot] = (unsigned short)s;
    }
}

// hs[N][DOUT] = (relu(A)[N][128] @ W[128][DOUT]) * dinv[row], fp16 out.
// MFMA 16x16x32 f16, f32 accumulate. 256 thr = 4 waves, 64 rows/block.
template <int DOUT, bool RELU, typename TIN>
__global__ __launch_bounds__(256) void mm_mfma_k(const TIN* __restrict__ A,
                                                 const _Float16* __restrict__ Wt,
                                                 const float* __restrict__ dinv,
                                                 _Float16* __restrict__ C) {
    constexpr int AST = 128 + 8;   // padded fp16 row stride (bank-spread)
    __shared__ _Float16 As[64 * AST];
    __shared__ _Float16 Ws[DOUT * AST];
    const int tid = threadIdx.x;
    const int rowBase = blockIdx.x * 64;

    // ---- stage A (convert to fp16, optional relu) ----
    if constexpr (sizeof(TIN) == 4) {
        for (int i = tid; i < 64 * 32; i += 256) {       // float4 granules
            int r = i >> 5;
            int k4 = (i & 31) * 4;
            int gr = rowBase + r;
            float4 v = make_float4(0.f, 0.f, 0.f, 0.f);
            if (gr < N_NODES) v = *(const float4*)((const float*)A + (size_t)gr * 128 + k4);
            if (RELU) {
                v.x = fmaxf(v.x, 0.f); v.y = fmaxf(v.y, 0.f);
                v.z = fmaxf(v.z, 0.f); v.w = fmaxf(v.w, 0.f);
            }
            half4_t hv;
            hv[0] = (_Float16)v.x; hv[1] = (_Float16)v.y;
            hv[2] = (_Float16)v.z; hv[3] = (_Float16)v.w;
            *(half4_t*)&As[r * AST + k4] = hv;
        }
    } else {
        for (int i = tid; i < 64 * 16; i += 256) {       // half8 granules
            int r = i >> 4;
            int k8 = (i & 15) * 8;
            int gr = rowBase + r;
            half8_t v = {};
            if (gr < N_NODES) v = *(const half8_t*)((const _Float16*)A + (size_t)gr * 128 + k8);
            if (RELU) {
#pragma unroll
                for (int j = 0; j < 8; ++j) v[j] = (v[j] > (_Float16)0) ? v[j] : (_Float16)0;
            }
            *(half8_t*)&As[r * AST + k8] = v;
        }
    }
    // ---- stage Wt ----
    for (int i = tid; i < DOUT * 16; i += 256) {
        int r = i >> 4;
        int k8 = (i & 15) * 8;
        *(half8_t*)&Ws[r * AST + k8] = *(const half8_t*)(Wt + r * 128 + k8);
    }
    __syncthreads();

    const int wid = tid >> 6;
    const int lane = tid & 63;
    const int l15 = lane & 15;
    const int lk = (lane >> 4) * 8;
    const int wrow = wid * 16;

    floatx4 acc[DOUT / 16];
#pragma unroll
    for (int t = 0; t < DOUT / 16; ++t) acc[t] = (floatx4){0.f, 0.f, 0.f, 0.f};

#pragma unroll
    for (int kc = 0; kc < 4; ++kc) {
        half8_t af = *(const half8_t*)&As[(wrow + l15) * AST + kc * 32 + lk];
#pragma unroll
        for (int ct = 0; ct < DOUT / 16; ++ct) {
            half8_t bf = *(const half8_t*)&Ws[(ct * 16 + l15) * AST + kc * 32 + lk];
            acc[ct] = __builtin_amdgcn_mfma_f32_16x16x32_f16(af, bf, acc[ct], 0, 0, 0);
        }
    }

    // D: row = (lane>>4)*4 + q, col = ct*16 + (lane&15)
    int rloc = wrow + (lane >> 4) * 4;
#pragma unroll
    for (int q = 0; q < 4; ++q) {
        int gr = rowBase + rloc + q;
        if (gr < N_NODES) {
            float dn = dinv[gr];
#pragma unroll
            for (int ct = 0; ct < DOUT / 16; ++ct) {
                C[(size_t)gr * DOUT + ct * 16 + l15] = (_Float16)(acc[ct][q] * dn);
            }
        }
    }
}

// Pull aggregation with pre-scaled features:
//   out[n] = dinv[n] * (sum_e hs[src[e]] + hs[n]) + b
template <int DOUT, bool F16OUT>
__global__ __launch_bounds__(256) void gather_k(const _Float16* __restrict__ h,
                                                const int* __restrict__ rowptr,
                                                const unsigned short* __restrict__ csr_src,
                                                const float* __restrict__ dinv,
                                                const float* __restrict__ b,
                                                void* __restrict__ out) {
    constexpr int TPN = DOUT / 8;
    constexpr int NPB = 256 / TPN;
    int n = blockIdx.x * NPB + threadIdx.x / TPN;
    int li = threadIdx.x % TPN;
    if (n >= N_NODES) return;
    const _Float16* hp = h + li * 8;
    int beg = rowptr[n];
    int end = rowptr[n + 1];
    float acc[8], acc2[8];
#pragma unroll
    for (int j = 0; j < 8; ++j) { acc[j] = 0.f; acc2[j] = 0.f; }
    int e = beg;
    for (; e + 4 <= end; e += 4) {
        int s0 = csr_src[e];
        int s1 = csr_src[e + 1];
        int s2 = csr_src[e + 2];
        int s3 = csr_src[e + 3];
        half8_t v0 = *(const half8_t*)(hp + (size_t)s0 * DOUT);
        half8_t v1 = *(const half8_t*)(hp + (size_t)s1 * DOUT);
        half8_t v2 = *(const half8_t*)(hp + (size_t)s2 * DOUT);
        half8_t v3 = *(const half8_t*)(hp + (size_t)s3 * DOUT);
#pragma unroll
        for (int j = 0; j < 8; ++j) {
            acc[j] += (float)v0[j];
            acc2[j] += (float)v1[j];
            acc[j] += (float)v2[j];
            acc2[j] += (float)v3[j];
        }
    }
    for (; e < end; ++e) {
        int s0 = csr_src[e];
        half8_t v0 = *(const half8_t*)(hp + (size_t)s0 * DOUT);
#pragma unroll
        for (int j = 0; j < 8; ++j) acc[j] += (float)v0[j];
    }
    float dn = dinv[n];
    half8_t hv = *(const half8_t*)(hp + (size_t)n * DOUT);
    float4 bv0 = *(const float4*)(b + li * 8);
    float4 bv1 = *(const float4*)(b + li * 8 + 4);
    float r[8];
    r[0] = (acc[0] + acc2[0] + (float)hv[0]) * dn + bv0.x;
    r[1] = (acc[1] + acc2[1] + (float)hv[1]) * dn + bv0.y;
    r[2] = (acc[2] + acc2[2] + (float)hv[2]) * dn + bv0.z;
    r[3] = (acc[3] + acc2[3] + (float)hv[3]) * dn + bv0.w;
    r[4] = (acc[4] + acc2[4] + (float)hv[4]) * dn + bv1.x;
    r[5] = (acc[5] + acc2[5] + (float)hv[5]) * dn + bv1.y;
    r[6] = (acc[6] + acc2[6] + (float)hv[6]) * dn + bv1.z;
    r[7] = (acc[7] + acc2[7] + (float)hv[7]) * dn + bv1.w;
    if constexpr (F16OUT) {
        half8_t o;
#pragma unroll
        for (int j = 0; j < 8; ++j) o[j] = (_Float16)r[j];
        *(half8_t*)((_Float16*)out + (size_t)n * DOUT + li * 8) = o;
    } else {
        float* op = (float*)out + (size_t)n * DOUT + li * 8;
        *(float4*)op = make_float4(r[0], r[1], r[2], r[3]);
        *(float4*)(op + 4) = make_float4(r[4], r[5], r[6], r[7]);
    }
}

extern "C" void kernel_launch(void* const* d_in, const int* in_sizes, int n_in,
                              void* d_out, int out_size, void* d_ws, size_t ws_size,
                              hipStream_t stream) {
    const float* x  = (const float*)d_in[0];
    const void*  ei = d_in[1];
    const float* W1 = (const float*)d_in[2];
    const float* b1 = (const float*)d_in[3];
    const float* W2 = (const float*)d_in[4];
    const float* b2 = (const float*)d_in[5];
    const float* W3 = (const float*)d_in[6];
    const float* b3 = (const float*)d_in[7];
    float* out = (float*)d_out;

    char* wsb = (char*)d_ws;
    size_t o = 0;
    int*            flag     = (int*)(wsb + o); o += 64 * 4;
    int*            cnt      = (int*)(wsb + o); o += 50048 * 4;
    float*          dinv     = (float*)(wsb + o); o += 50048 * 4;
    int*            rowptr   = (int*)(wsb + o); o += 50056 * 4;
    int*            blocksum = (int*)(wsb + o); o += 64 * 4;
    int*            bcur     = (int*)(wsb + o); o += 448 * 4;
    unsigned int*   ep       = (unsigned int*)(wsb + o); o += (size_t)N_EDGES * 4;
    unsigned int*   ep2      = (unsigned int*)(wsb + o); o += (size_t)N_EDGES * 4;
    unsigned short* csr_src  = (unsigned short*)(wsb + o); o += (size_t)N_EDGES * 2;
    _Float16*       Wt1      = (_Float16*)(wsb + o); o += 128 * 128 * 2;
    _Float16*       Wt2      = (_Float16*)(wsb + o); o += 128 * 128 * 2;
    _Float16*       Wt3      = (_Float16*)(wsb + o); o += 64 * 128 * 2;
    _Float16*       h        = (_Float16*)(wsb + o); o += (size_t)N_NODES * 128 * 2;
    _Float16*       agg      = (_Float16*)(wsb + o);

    const int NB_N = (N_NODES + 255) / 256;   // 196
    const int NB_E = (N_EDGES + 255) / 256;   // 3125
    const int MMB  = (N_NODES + 63) / 64;     // 782

    // ---- graph preprocessing (once; reused by all 3 layers) ----
    init_k<<<NB_N, 256, 0, stream>>>((const int*)ei, flag, cnt, W1, W2, W3, Wt1, Wt2, Wt3);
    deg_compact_k<<<NB_E, 256, 0, stream>>>(ei, flag, cnt, ep);
    scan_pass1_k<<<SCAN_BLOCKS, 1024, 0, stream>>>(cnt, rowptr, blocksum, dinv);
    scan_pass2_k<<<1, 64, 0, stream>>>(blocksum, rowptr);
    scan_pass3_k<<<NB_N, 256, 0, stream>>>(rowptr, blocksum, bcur);
    bucketA_k<<<NWG_A, 256, 0, stream>>>(ep, bcur, ep2);
    bucketB_k<<<NBKT, 256, 0, stream>>>(ep2, rowptr, csr_src);

    // ---- layer 1 ----
    mm_mfma_k<128, false, float><<<MMB, 256, 0, stream>>>(x, Wt1, dinv, h);
    gather_k<128, true><<<(N_NODES + 15) / 16, 256, 0, stream>>>(h, rowptr, csr_src, dinv, b1, agg);

    // ---- layer 2 ----
    mm_mfma_k<128, true, _Float16><<<MMB, 256, 0, stream>>>(agg, Wt2, dinv, h);
    gather_k<128, true><<<(N_NODES + 15) / 16, 256, 0, stream>>>(h, rowptr, csr_src, dinv, b2, agg);

    // ---- layer 3 (to d_out, f32) ----
    mm_mfma_k<64, true, _Float16><<<MMB, 256, 0, stream>>>(agg, Wt3, dinv, h);
    gather_k<64, false><<<(N_NODES + 31) / 32, 256, 0, stream>>>(h, rowptr, csr_src, dinv, b3, out);
}